// Round 1
// baseline (11140.918 us; speedup 1.0000x reference)
//
#include <hip/hip_runtime.h>
#include <hip/hip_bf16.h>
#include <math.h>

// Problem constants (fixed by reference)
#define T_STEPS 24
#define N_NODES 20000
#define F_IN 64
#define H_DIM 256
#define H3 (3 * H_DIM)

// ---------------------------------------------------------------------------
// Norm / CSR build kernels
// ---------------------------------------------------------------------------

__global__ void init_deg_kernel(float* deg, int* indeg, int n) {
    int i = blockIdx.x * blockDim.x + threadIdx.x;
    if (i < n) { deg[i] = 1.0f; indeg[i] = 0; }
}

__global__ void accum_deg_kernel(const int* __restrict__ src, const int* __restrict__ dst,
                                 const float* __restrict__ ew, float* deg, int* indeg, int E) {
    int e = blockIdx.x * blockDim.x + threadIdx.x;
    if (e < E) {
        atomicAdd(&deg[dst[e]], ew[e]);
        atomicAdd(&indeg[dst[e]], 1);
    }
}

__global__ void dinv_kernel(float* deg /* in: deg, out: dinv */, float* selfnorm, int n) {
    int i = blockIdx.x * blockDim.x + threadIdx.x;
    if (i < n) {
        float d = deg[i];
        float di = (d > 0.0f) ? rsqrtf(d) : 0.0f;
        deg[i] = di;
        selfnorm[i] = di * di;
    }
}

__global__ void edge_norm_kernel(const int* __restrict__ src, const int* __restrict__ dst,
                                 const float* __restrict__ ew, const float* __restrict__ dinv,
                                 float* norm, int E) {
    int e = blockIdx.x * blockDim.x + threadIdx.x;
    if (e < E) norm[e] = dinv[src[e]] * ew[e] * dinv[dst[e]];
}

// Single-block exclusive scan of indeg -> offs (N+1), cursor copy.
__global__ void scan_kernel(const int* __restrict__ indeg, int* offs, int* cursor, int N) {
    __shared__ int part[1024];
    int t = threadIdx.x;
    const int CH = (N + 1023) / 1024;
    int s = 0;
    for (int i = 0; i < CH; i++) {
        int idx = t * CH + i;
        if (idx < N) s += indeg[idx];
    }
    part[t] = s;
    __syncthreads();
    for (int off = 1; off < 1024; off <<= 1) {
        int v = (t >= off) ? part[t - off] : 0;
        __syncthreads();
        part[t] += v;
        __syncthreads();
    }
    int base = (t == 0) ? 0 : part[t - 1];
    for (int i = 0; i < CH; i++) {
        int idx = t * CH + i;
        if (idx < N) {
            offs[idx] = base;
            cursor[idx] = base;
            base += indeg[idx];
        }
    }
    if (t == 0) offs[N] = part[1023];
}

__global__ void csr_fill_kernel(const int* __restrict__ src, const int* __restrict__ dst,
                                const float* __restrict__ norm, int* cursor,
                                int* csr_src, float* csr_norm, int E) {
    int e = blockIdx.x * blockDim.x + threadIdx.x;
    if (e < E) {
        int d = dst[e];
        int pos = atomicAdd(&cursor[d], 1);
        csr_src[pos] = src[e];
        csr_norm[pos] = norm[e];
    }
}

// ---------------------------------------------------------------------------
// GEMM: C[M,N] = A[M,K] * op(B) (+ bias[col]); BT: B is [N,K] row-major (use B^T)
// Tile 64x64x16, 256 threads, 4x4 per thread, fp32 vector FMA.
// ---------------------------------------------------------------------------
template <bool BT>
__global__ void gemm_kernel(const float* __restrict__ A, const float* __restrict__ B,
                            const float* __restrict__ bias, float* __restrict__ C,
                            int M, int N, int K) {
    constexpr int BM = 64, BN = 64, BK = 16;
    __shared__ float As[BK][BM];
    __shared__ float Bs[BK][BN];
    const int t = threadIdx.x;
    const int bm = blockIdx.x * BM;
    const int bn = blockIdx.y * BN;
    const int tm = (t >> 4) << 2;  // 0..60
    const int tn = (t & 15) << 2;  // 0..60

    float acc[4][4] = {};

    for (int k0 = 0; k0 < K; k0 += BK) {
        // Load A tile: 64 rows x 16 k. thread: row=t>>2, kc=(t&3)*4
        {
            int r = t >> 2, kc = (t & 3) << 2;
            int gr = bm + r;
            float4 v = make_float4(0.f, 0.f, 0.f, 0.f);
            if (gr < M) v = *(const float4*)&A[(size_t)gr * K + k0 + kc];
            As[kc + 0][r] = v.x; As[kc + 1][r] = v.y; As[kc + 2][r] = v.z; As[kc + 3][r] = v.w;
        }
        if (!BT) {
            // B[K,N] row-major: row k0+r, cols bn+c..c+3
            int r = t >> 4, c = (t & 15) << 2;
            float4 v = *(const float4*)&B[(size_t)(k0 + r) * N + bn + c];
            Bs[r][c + 0] = v.x; Bs[r][c + 1] = v.y; Bs[r][c + 2] = v.z; Bs[r][c + 3] = v.w;
        } else {
            // B'[N,K] row-major: need Bs[k][c] = B'[bn+c][k0+k]
            int c = t >> 2, kc = (t & 3) << 2;
            float4 v = *(const float4*)&B[(size_t)(bn + c) * K + k0 + kc];
            Bs[kc + 0][c] = v.x; Bs[kc + 1][c] = v.y; Bs[kc + 2][c] = v.z; Bs[kc + 3][c] = v.w;
        }
        __syncthreads();

#pragma unroll
        for (int k = 0; k < BK; k++) {
            float a[4], b[4];
            *(float4*)a = *(const float4*)&As[k][tm];
            *(float4*)b = *(const float4*)&Bs[k][tn];
#pragma unroll
            for (int i = 0; i < 4; i++)
#pragma unroll
                for (int j = 0; j < 4; j++) acc[i][j] = fmaf(a[i], b[j], acc[i][j]);
        }
        __syncthreads();
    }

    float bj[4] = {0.f, 0.f, 0.f, 0.f};
    if (bias) { *(float4*)bj = *(const float4*)&bias[bn + tn]; }
#pragma unroll
    for (int i = 0; i < 4; i++) {
        int gr = bm + tm + i;
        if (gr < M) {
            float4 o;
            o.x = acc[i][0] + bj[0];
            o.y = acc[i][1] + bj[1];
            o.z = acc[i][2] + bj[2];
            o.w = acc[i][3] + bj[3];
            *(float4*)&C[(size_t)gr * N + bn + tn] = o;
        }
    }
}

// ---------------------------------------------------------------------------
// GCN aggregation: out[n][f] = act(b[f] + selfnorm[n]*h[n][f] + sum_e norm*h[src][f])
// One block (256 threads) per node.
// ---------------------------------------------------------------------------
template <bool LEAKY>
__global__ void gcn_agg_kernel(const float* __restrict__ h, const int* __restrict__ offs,
                               const int* __restrict__ csr_src, const float* __restrict__ csr_norm,
                               const float* __restrict__ selfnorm, const float* __restrict__ bias,
                               float* __restrict__ out) {
    int n = blockIdx.x;
    int f = threadIdx.x;
    float acc = selfnorm[n] * h[(size_t)n * H_DIM + f];
    int e0 = offs[n], e1 = offs[n + 1];
    for (int e = e0; e < e1; e++) {
        int s = csr_src[e];
        float w = csr_norm[e];
        acc = fmaf(w, h[(size_t)s * H_DIM + f], acc);
    }
    acc += bias[f];
    if (LEAKY) acc = (acc >= 0.0f) ? acc : 0.01f * acc;
    out[(size_t)n * H_DIM + f] = acc;
}

// ---------------------------------------------------------------------------
// LayerNorm over 256 features, one block per row.
// ---------------------------------------------------------------------------
__global__ void layernorm_kernel(const float* __restrict__ in, const float* __restrict__ w,
                                 const float* __restrict__ b, float* __restrict__ out) {
    int n = blockIdx.x;
    int f = threadIdx.x;
    float v = in[(size_t)n * H_DIM + f];
    float s = v, s2 = v * v;
#pragma unroll
    for (int o = 32; o > 0; o >>= 1) {
        s += __shfl_down(s, o, 64);
        s2 += __shfl_down(s2, o, 64);
    }
    __shared__ float ps[4], ps2[4];
    int wid = f >> 6;
    if ((f & 63) == 0) { ps[wid] = s; ps2[wid] = s2; }
    __syncthreads();
    float S = ps[0] + ps[1] + ps[2] + ps[3];
    float S2 = ps2[0] + ps2[1] + ps2[2] + ps2[3];
    float mu = S * (1.0f / H_DIM);
    float var = S2 * (1.0f / H_DIM) - mu * mu;
    float rstd = rsqrtf(var + 1e-5f);
    out[(size_t)n * H_DIM + f] = (v - mu) * rstd * w[f] + b[f];
}

// ---------------------------------------------------------------------------
// GRU pointwise: gates + state update (in-place h).
// gi/gh layout: [N, 3H] with (r | z | n) thirds.
// ---------------------------------------------------------------------------
__device__ __forceinline__ float sigmoidf_(float x) { return 1.0f / (1.0f + expf(-x)); }

__global__ void gru_pw_kernel(const float* __restrict__ gi, const float* __restrict__ gh,
                              float* __restrict__ h) {
    int idx = blockIdx.x * blockDim.x + threadIdx.x;
    if (idx >= N_NODES * H_DIM) return;
    int n = idx >> 8;        // /256
    int j = idx & (H_DIM - 1);
    const float* gin = gi + (size_t)n * H3;
    const float* ghn = gh + (size_t)n * H3;
    float r = sigmoidf_(gin[j] + ghn[j]);
    float z = sigmoidf_(gin[H_DIM + j] + ghn[H_DIM + j]);
    float nn = tanhf(gin[2 * H_DIM + j] + r * ghn[2 * H_DIM + j]);
    float hp = h[idx];
    h[idx] = (1.0f - z) * nn + z * hp;
}

// ---------------------------------------------------------------------------
// fc: out[n] = dot(h[n,:], Wfc[0,:]) + bfc. One wave per node, 4 nodes/block.
// ---------------------------------------------------------------------------
__global__ void fc_kernel(const float* __restrict__ h, const float* __restrict__ Wfc,
                          const float* __restrict__ bfc, float* __restrict__ out, int N) {
    int n = blockIdx.x * 4 + (threadIdx.x >> 6);
    int lane = threadIdx.x & 63;
    if (n >= N) return;
    float4 hv = *(const float4*)&h[(size_t)n * H_DIM + lane * 4];
    float4 wv = *(const float4*)&Wfc[lane * 4];
    float acc = hv.x * wv.x + hv.y * wv.y + hv.z * wv.z + hv.w * wv.w;
#pragma unroll
    for (int o = 32; o > 0; o >>= 1) acc += __shfl_down(acc, o, 64);
    if (lane == 0) out[n] = acc + bfc[0];
}

// ---------------------------------------------------------------------------
// Launch
// ---------------------------------------------------------------------------
extern "C" void kernel_launch(void* const* d_in, const int* in_sizes, int n_in,
                              void* d_out, int out_size, void* d_ws, size_t ws_size,
                              hipStream_t stream) {
    const float* x   = (const float*)d_in[0];   // [T,N,F_IN]
    const int* eidx  = (const int*)d_in[1];     // [2,E]
    const float* ew  = (const float*)d_in[2];   // [E]
    const float* W1  = (const float*)d_in[3];   // [F_IN,H]
    const float* b1  = (const float*)d_in[4];
    const float* W2  = (const float*)d_in[5];   // [H,H]
    const float* b2  = (const float*)d_in[6];
    const float* lnw = (const float*)d_in[7];
    const float* lnb = (const float*)d_in[8];
    const float* Wih = (const float*)d_in[9];   // [3H,H]
    const float* Whh = (const float*)d_in[10];  // [3H,H]
    const float* bih = (const float*)d_in[11];
    const float* bhh = (const float*)d_in[12];
    const float* Wfc = (const float*)d_in[13];  // [1,H]
    const float* bfc = (const float*)d_in[14];

    const int E = in_sizes[2];
    const int N = N_NODES;
    const int* src = eidx;
    const int* dst = eidx + E;

    // Workspace bump allocator (256B aligned)
    uintptr_t p = (uintptr_t)d_ws;
    auto alloc = [&](size_t bytes) -> void* {
        p = (p + 255) & ~(uintptr_t)255;
        void* r = (void*)p;
        p += bytes;
        return r;
    };
    float* deg      = (float*)alloc(N * sizeof(float));   // becomes dinv
    float* selfnorm = (float*)alloc(N * sizeof(float));
    float* norm     = (float*)alloc(E * sizeof(float));
    int* indeg      = (int*)alloc(N * sizeof(int));
    int* offs       = (int*)alloc((N + 1) * sizeof(int));
    int* cursor     = (int*)alloc(N * sizeof(int));
    int* csr_src    = (int*)alloc(E * sizeof(int));
    float* csr_norm = (float*)alloc(E * sizeof(float));
    float* bufA     = (float*)alloc((size_t)N * H_DIM * sizeof(float));
    float* bufB     = (float*)alloc((size_t)N * H_DIM * sizeof(float));
    float* enc      = (float*)alloc((size_t)N * H_DIM * sizeof(float));
    float* hstate   = (float*)alloc((size_t)N * H_DIM * sizeof(float));
    float* gi       = (float*)alloc((size_t)N * H3 * sizeof(float));
    float* gh       = (float*)alloc((size_t)N * H3 * sizeof(float));

    const int TB = 256;
    // --- norm + CSR (once per launch) ---
    hipLaunchKernelGGL(init_deg_kernel, dim3((N + TB - 1) / TB), dim3(TB), 0, stream, deg, indeg, N);
    hipLaunchKernelGGL(accum_deg_kernel, dim3((E + TB - 1) / TB), dim3(TB), 0, stream, src, dst, ew, deg, indeg, E);
    hipLaunchKernelGGL(dinv_kernel, dim3((N + TB - 1) / TB), dim3(TB), 0, stream, deg, selfnorm, N);
    hipLaunchKernelGGL(edge_norm_kernel, dim3((E + TB - 1) / TB), dim3(TB), 0, stream, src, dst, ew, deg, norm, E);
    hipLaunchKernelGGL(scan_kernel, dim3(1), dim3(1024), 0, stream, indeg, offs, cursor, N);
    hipLaunchKernelGGL(csr_fill_kernel, dim3((E + TB - 1) / TB), dim3(TB), 0, stream, src, dst, norm, cursor, csr_src, csr_norm, E);

    // h0 = 0
    hipMemsetAsync(hstate, 0, (size_t)N * H_DIM * sizeof(float), stream);

    dim3 gemm_block(256);
    dim3 g_conv1((N + 63) / 64, H_DIM / 64);
    dim3 g_conv2((N + 63) / 64, H_DIM / 64);
    dim3 g_gru((N + 63) / 64, H3 / 64);

    for (int t = 0; t < T_STEPS; t++) {
        const float* xt = x + (size_t)t * N * F_IN;
        // conv1: bufA = xt @ W1
        hipLaunchKernelGGL((gemm_kernel<false>), g_conv1, gemm_block, 0, stream,
                           xt, W1, (const float*)nullptr, bufA, N, H_DIM, F_IN);
        // aggregate + b1 + leaky -> bufB
        hipLaunchKernelGGL((gcn_agg_kernel<true>), dim3(N), dim3(H_DIM), 0, stream,
                           bufA, offs, csr_src, csr_norm, selfnorm, b1, bufB);
        // conv2: bufA = bufB @ W2
        hipLaunchKernelGGL((gemm_kernel<false>), g_conv2, gemm_block, 0, stream,
                           bufB, W2, (const float*)nullptr, bufA, N, H_DIM, H_DIM);
        // aggregate + b2 -> bufB
        hipLaunchKernelGGL((gcn_agg_kernel<false>), dim3(N), dim3(H_DIM), 0, stream,
                           bufA, offs, csr_src, csr_norm, selfnorm, b2, bufB);
        // layernorm -> enc
        hipLaunchKernelGGL(layernorm_kernel, dim3(N), dim3(H_DIM), 0, stream, bufB, lnw, lnb, enc);
        // GRU: gi = enc @ Wih^T + bih ; gh = h @ Whh^T + bhh
        hipLaunchKernelGGL((gemm_kernel<true>), g_gru, gemm_block, 0, stream,
                           enc, Wih, bih, gi, N, H3, H_DIM);
        hipLaunchKernelGGL((gemm_kernel<true>), g_gru, gemm_block, 0, stream,
                           hstate, Whh, bhh, gh, N, H3, H_DIM);
        hipLaunchKernelGGL(gru_pw_kernel, dim3((N * H_DIM + TB - 1) / TB), dim3(TB), 0, stream, gi, gh, hstate);
    }

    // fc
    hipLaunchKernelGGL(fc_kernel, dim3((N + 3) / 4), dim3(256), 0, stream, hstate, Wfc, bfc, (float*)d_out, N);
}

// Round 2
// 8304.406 us; speedup vs baseline: 1.3416x; 1.3416x over previous
//
#include <hip/hip_runtime.h>
#include <math.h>

// Problem constants (fixed by reference)
#define T_STEPS 24
#define N_NODES 20000
#define F_IN 64
#define H_DIM 256
#define H3 (3 * H_DIM)

typedef unsigned short ushort_t;
using bf16x8 = __attribute__((ext_vector_type(8))) __bf16;
using f32x4  = __attribute__((ext_vector_type(4))) float;

// ---------------------------------------------------------------------------
// bf16 split helpers (RNE)
// ---------------------------------------------------------------------------
__device__ __forceinline__ unsigned short f2bf(float x) {
    unsigned int u = __float_as_uint(x);
    u += 0x7fff + ((u >> 16) & 1);
    return (unsigned short)(u >> 16);
}
__device__ __forceinline__ float bf2f(unsigned short h) {
    return __uint_as_float(((unsigned int)h) << 16);
}
__device__ __forceinline__ void split2(float x, unsigned short& hi, unsigned short& lo) {
    unsigned short h = f2bf(x);
    hi = h;
    lo = f2bf(x - bf2f(h));
}

__device__ __forceinline__ void gload_lds16(const void* g, void* l) {
    __builtin_amdgcn_global_load_lds(
        (const __attribute__((address_space(1))) void*)(uintptr_t)g,
        (__attribute__((address_space(3))) void*)l, 16, 0, 0);
}

// ---------------------------------------------------------------------------
// Norm / CSR build kernels
// ---------------------------------------------------------------------------
__global__ void init_deg_kernel(float* deg, int* indeg, int n) {
    int i = blockIdx.x * blockDim.x + threadIdx.x;
    if (i < n) { deg[i] = 1.0f; indeg[i] = 0; }
}

__global__ void accum_deg_kernel(const int* __restrict__ src, const int* __restrict__ dst,
                                 const float* __restrict__ ew, float* deg, int* indeg, int E) {
    int e = blockIdx.x * blockDim.x + threadIdx.x;
    if (e < E) {
        atomicAdd(&deg[dst[e]], ew[e]);
        atomicAdd(&indeg[dst[e]], 1);
    }
}

__global__ void dinv_kernel(float* deg, float* selfnorm, int n) {
    int i = blockIdx.x * blockDim.x + threadIdx.x;
    if (i < n) {
        float d = deg[i];
        float di = (d > 0.0f) ? rsqrtf(d) : 0.0f;
        deg[i] = di;
        selfnorm[i] = di * di;
    }
}

__global__ void edge_norm_kernel(const int* __restrict__ src, const int* __restrict__ dst,
                                 const float* __restrict__ ew, const float* __restrict__ dinv,
                                 float* norm, int E) {
    int e = blockIdx.x * blockDim.x + threadIdx.x;
    if (e < E) norm[e] = dinv[src[e]] * ew[e] * dinv[dst[e]];
}

__global__ void scan_kernel(const int* __restrict__ indeg, int* offs, int* cursor, int N) {
    __shared__ int part[1024];
    int t = threadIdx.x;
    const int CH = (N + 1023) / 1024;
    int s = 0;
    for (int i = 0; i < CH; i++) {
        int idx = t * CH + i;
        if (idx < N) s += indeg[idx];
    }
    part[t] = s;
    __syncthreads();
    for (int off = 1; off < 1024; off <<= 1) {
        int v = (t >= off) ? part[t - off] : 0;
        __syncthreads();
        part[t] += v;
        __syncthreads();
    }
    int base = (t == 0) ? 0 : part[t - 1];
    for (int i = 0; i < CH; i++) {
        int idx = t * CH + i;
        if (idx < N) {
            offs[idx] = base;
            cursor[idx] = base;
            base += indeg[idx];
        }
    }
    if (t == 0) offs[N] = part[1023];
}

__global__ void csr_fill_kernel(const int* __restrict__ src, const int* __restrict__ dst,
                                const float* __restrict__ norm, int* cursor,
                                int* csr_src, float* csr_norm, int E) {
    int e = blockIdx.x * blockDim.x + threadIdx.x;
    if (e < E) {
        int d = dst[e];
        int pos = atomicAdd(&cursor[d], 1);
        csr_src[pos] = src[e];
        csr_norm[pos] = norm[e];
    }
}

// ---------------------------------------------------------------------------
// Weight pack: P[kk][n][j] (hi/lo bf16) for j=0..7, kk=k/8.
// trans=0: B = W [K,N] row-major.  trans=1: B = W^T with W [N,K] row-major.
// ---------------------------------------------------------------------------
__global__ void pack_b_kernel(const float* __restrict__ W, ushort_t* __restrict__ Phi,
                              ushort_t* __restrict__ Plo, int K, int Nn, int trans) {
    int idx = blockIdx.x * blockDim.x + threadIdx.x;
    int total = (K >> 3) * Nn;
    if (idx >= total) return;
    int kk = idx / Nn, n = idx - kk * Nn;
    size_t o = (size_t)idx * 8;
    for (int j = 0; j < 8; ++j) {
        float v = trans ? W[(size_t)n * K + kk * 8 + j] : W[(size_t)(kk * 8 + j) * Nn + n];
        ushort_t h, l;
        split2(v, h, l);
        Phi[o + j] = h;
        Plo[o + j] = l;
    }
}

// Split a fp32 array into bf16 hi/lo arrays
__global__ void split_kernel(const float* __restrict__ in, ushort_t* __restrict__ hi,
                             ushort_t* __restrict__ lo, int n) {
    int i = blockIdx.x * blockDim.x + threadIdx.x;
    if (i < n) split2(in[i], hi[i], lo[i]);
}

// ---------------------------------------------------------------------------
// Split-bf16 MFMA GEMM: C[M,Nn] = (Ahi+Alo)[M,K] @ (Bhi+Blo)[K,Nn] (+bias)
// 128x128 tile, BK=32, 256 threads = 4 waves (2x2), 16x16x32 bf16 MFMA,
// 3 MFMAs per frag pair (hi*hi + hi*lo + lo*hi).
// A: row-major bf16 [M,K]. B: packed [K/8][Nn][8].
// ---------------------------------------------------------------------------
__global__ __launch_bounds__(256, 2)
void gemm_split_kernel(const ushort_t* __restrict__ Ahi, const ushort_t* __restrict__ Alo,
                       const ushort_t* __restrict__ Bhi, const ushort_t* __restrict__ Blo,
                       const float* __restrict__ bias, float* __restrict__ C,
                       int M, int Nn, int K) {
    __shared__ ushort_t Ah[4][128][8];
    __shared__ ushort_t Al[4][128][8];
    __shared__ ushort_t Bh[4][128][8];
    __shared__ ushort_t Bl[4][128][8];

    const int tid = threadIdx.x;
    const int wave = tid >> 6, lane = tid & 63;
    const int bm = blockIdx.x * 128, bn = blockIdx.y * 128;
    const int wm = (wave >> 1) * 64, wn = (wave & 1) * 64;
    const int kq = lane >> 4, r = lane & 15;

    f32x4 acc[4][4];
#pragma unroll
    for (int i = 0; i < 4; ++i)
#pragma unroll
        for (int j = 0; j < 4; ++j) acc[i][j] = (f32x4){0.f, 0.f, 0.f, 0.f};

    for (int k0 = 0; k0 < K; k0 += 32) {
        __syncthreads();
        const int kb = k0 >> 3;
#pragma unroll
        for (int it = 0; it < 2; ++it) {
            int c = it * 256 + tid;          // chunk 0..511
            int kk = c >> 7, idx = c & 127;
            int row = bm + idx;
            if (row >= M) row = M - 1;
            size_t aoff = (size_t)row * K + k0 + kk * 8;
            size_t boff = ((size_t)(kb + kk) * Nn + bn + idx) * 8;
            int lbase = (it * 256 + wave * 64) * 8;   // ushort units
            gload_lds16(Ahi + aoff, &Ah[0][0][0] + lbase);
            gload_lds16(Alo + aoff, &Al[0][0][0] + lbase);
            gload_lds16(Bhi + boff, &Bh[0][0][0] + lbase);
            gload_lds16(Blo + boff, &Bl[0][0][0] + lbase);
        }
        __syncthreads();

        bf16x8 ah[4], al[4], bh[4], bl[4];
#pragma unroll
        for (int f = 0; f < 4; ++f) {
            ah[f] = *(const bf16x8*)&Ah[kq][wm + f * 16 + r][0];
            al[f] = *(const bf16x8*)&Al[kq][wm + f * 16 + r][0];
            bh[f] = *(const bf16x8*)&Bh[kq][wn + f * 16 + r][0];
            bl[f] = *(const bf16x8*)&Bl[kq][wn + f * 16 + r][0];
        }
#pragma unroll
        for (int i = 0; i < 4; ++i)
#pragma unroll
            for (int j = 0; j < 4; ++j) {
                acc[i][j] = __builtin_amdgcn_mfma_f32_16x16x32_bf16(ah[i], bh[j], acc[i][j], 0, 0, 0);
                acc[i][j] = __builtin_amdgcn_mfma_f32_16x16x32_bf16(ah[i], bl[j], acc[i][j], 0, 0, 0);
                acc[i][j] = __builtin_amdgcn_mfma_f32_16x16x32_bf16(al[i], bh[j], acc[i][j], 0, 0, 0);
            }
    }

    // Epilogue: C/D layout col = lane&15, row = (lane>>4)*4 + reg  [m89]
#pragma unroll
    for (int j = 0; j < 4; ++j) {
        int col = bn + wn + j * 16 + r;
        float bv = bias ? bias[col] : 0.0f;
#pragma unroll
        for (int i = 0; i < 4; ++i) {
#pragma unroll
            for (int q = 0; q < 4; ++q) {
                int row = bm + wm + i * 16 + kq * 4 + q;
                if (row < M) C[(size_t)row * Nn + col] = acc[i][j][q] + bv;
            }
        }
    }
}

// ---------------------------------------------------------------------------
// GCN aggregation: out[n][f] = act(b[f] + selfnorm[n]*h[n][f] + sum_e norm*h[src][f])
// One block (256 threads) per node. SPLIT: write bf16 hi/lo. else fp32.
// ---------------------------------------------------------------------------
template <bool LEAKY, bool SPLIT>
__global__ void gcn_agg_kernel(const float* __restrict__ h, const int* __restrict__ offs,
                               const int* __restrict__ csr_src, const float* __restrict__ csr_norm,
                               const float* __restrict__ selfnorm, const float* __restrict__ bias,
                               float* __restrict__ outf, ushort_t* __restrict__ outh,
                               ushort_t* __restrict__ outl) {
    int n = blockIdx.x;
    int f = threadIdx.x;
    float acc = selfnorm[n] * h[(size_t)n * H_DIM + f];
    int e0 = offs[n], e1 = offs[n + 1];
    for (int e = e0; e < e1; e++) {
        int s = csr_src[e];
        float w = csr_norm[e];
        acc = fmaf(w, h[(size_t)s * H_DIM + f], acc);
    }
    acc += bias[f];
    if (LEAKY) acc = (acc >= 0.0f) ? acc : 0.01f * acc;
    size_t o = (size_t)n * H_DIM + f;
    if (SPLIT) {
        ushort_t hh, ll;
        split2(acc, hh, ll);
        outh[o] = hh;
        outl[o] = ll;
    } else {
        outf[o] = acc;
    }
}

// ---------------------------------------------------------------------------
// LayerNorm over 256 features -> bf16 hi/lo output
// ---------------------------------------------------------------------------
__global__ void layernorm_kernel(const float* __restrict__ in, const float* __restrict__ w,
                                 const float* __restrict__ b, ushort_t* __restrict__ outh,
                                 ushort_t* __restrict__ outl) {
    int n = blockIdx.x;
    int f = threadIdx.x;
    float v = in[(size_t)n * H_DIM + f];
    float s = v, s2 = v * v;
#pragma unroll
    for (int o = 32; o > 0; o >>= 1) {
        s += __shfl_down(s, o, 64);
        s2 += __shfl_down(s2, o, 64);
    }
    __shared__ float ps[4], ps2[4];
    int wid = f >> 6;
    if ((f & 63) == 0) { ps[wid] = s; ps2[wid] = s2; }
    __syncthreads();
    float S = ps[0] + ps[1] + ps[2] + ps[3];
    float S2 = ps2[0] + ps2[1] + ps2[2] + ps2[3];
    float mu = S * (1.0f / H_DIM);
    float var = S2 * (1.0f / H_DIM) - mu * mu;
    float rstd = rsqrtf(var + 1e-5f);
    float outv = (v - mu) * rstd * w[f] + b[f];
    size_t o = (size_t)n * H_DIM + f;
    ushort_t hh, ll;
    split2(outv, hh, ll);
    outh[o] = hh;
    outl[o] = ll;
}

// ---------------------------------------------------------------------------
// GRU pointwise; writes h (fp32) and its bf16 hi/lo split.
// ---------------------------------------------------------------------------
__device__ __forceinline__ float sigmoidf_(float x) { return 1.0f / (1.0f + expf(-x)); }

__global__ void gru_pw_kernel(const float* __restrict__ gi, const float* __restrict__ gh,
                              float* __restrict__ h, ushort_t* __restrict__ hhi,
                              ushort_t* __restrict__ hlo) {
    int idx = blockIdx.x * blockDim.x + threadIdx.x;
    if (idx >= N_NODES * H_DIM) return;
    int n = idx >> 8;
    int j = idx & (H_DIM - 1);
    const float* gin = gi + (size_t)n * H3;
    const float* ghn = gh + (size_t)n * H3;
    float r = sigmoidf_(gin[j] + ghn[j]);
    float z = sigmoidf_(gin[H_DIM + j] + ghn[H_DIM + j]);
    float nn = tanhf(gin[2 * H_DIM + j] + r * ghn[2 * H_DIM + j]);
    float hp = h[idx];
    float hv = (1.0f - z) * nn + z * hp;
    h[idx] = hv;
    ushort_t hh, ll;
    split2(hv, hh, ll);
    hhi[idx] = hh;
    hlo[idx] = ll;
}

// ---------------------------------------------------------------------------
// fc: out[n] = dot(h[n,:], Wfc[0,:]) + bfc
// ---------------------------------------------------------------------------
__global__ void fc_kernel(const float* __restrict__ h, const float* __restrict__ Wfc,
                          const float* __restrict__ bfc, float* __restrict__ out, int N) {
    int n = blockIdx.x * 4 + (threadIdx.x >> 6);
    int lane = threadIdx.x & 63;
    if (n >= N) return;
    float4 hv = *(const float4*)&h[(size_t)n * H_DIM + lane * 4];
    float4 wv = *(const float4*)&Wfc[lane * 4];
    float acc = hv.x * wv.x + hv.y * wv.y + hv.z * wv.z + hv.w * wv.w;
#pragma unroll
    for (int o = 32; o > 0; o >>= 1) acc += __shfl_down(acc, o, 64);
    if (lane == 0) out[n] = acc + bfc[0];
}

// ---------------------------------------------------------------------------
// Launch
// ---------------------------------------------------------------------------
extern "C" void kernel_launch(void* const* d_in, const int* in_sizes, int n_in,
                              void* d_out, int out_size, void* d_ws, size_t ws_size,
                              hipStream_t stream) {
    const float* x   = (const float*)d_in[0];
    const int* eidx  = (const int*)d_in[1];
    const float* ew  = (const float*)d_in[2];
    const float* W1  = (const float*)d_in[3];
    const float* b1  = (const float*)d_in[4];
    const float* W2  = (const float*)d_in[5];
    const float* b2  = (const float*)d_in[6];
    const float* lnw = (const float*)d_in[7];
    const float* lnb = (const float*)d_in[8];
    const float* Wih = (const float*)d_in[9];
    const float* Whh = (const float*)d_in[10];
    const float* bih = (const float*)d_in[11];
    const float* bhh = (const float*)d_in[12];
    const float* Wfc = (const float*)d_in[13];
    const float* bfc = (const float*)d_in[14];

    const int E = in_sizes[2];
    const int N = N_NODES;
    const int* src = eidx;
    const int* dst = eidx + E;

    uintptr_t p = (uintptr_t)d_ws;
    auto alloc = [&](size_t bytes) -> void* {
        p = (p + 255) & ~(uintptr_t)255;
        void* r = (void*)p;
        p += bytes;
        return r;
    };
    // CSR / norm
    float* deg      = (float*)alloc(N * sizeof(float));
    float* selfnorm = (float*)alloc(N * sizeof(float));
    float* norm     = (float*)alloc(E * sizeof(float));
    int* indeg      = (int*)alloc(N * sizeof(int));
    int* offs       = (int*)alloc((N + 1) * sizeof(int));
    int* cursor     = (int*)alloc(N * sizeof(int));
    int* csr_src    = (int*)alloc(E * sizeof(int));
    float* csr_norm = (float*)alloc(E * sizeof(float));
    // split inputs / weights
    ushort_t* xs_hi = (ushort_t*)alloc((size_t)N * F_IN * sizeof(ushort_t));
    ushort_t* xs_lo = (ushort_t*)alloc((size_t)N * F_IN * sizeof(ushort_t));
    ushort_t* W1ph  = (ushort_t*)alloc((size_t)F_IN * H_DIM * sizeof(ushort_t));
    ushort_t* W1pl  = (ushort_t*)alloc((size_t)F_IN * H_DIM * sizeof(ushort_t));
    ushort_t* W2ph  = (ushort_t*)alloc((size_t)H_DIM * H_DIM * sizeof(ushort_t));
    ushort_t* W2pl  = (ushort_t*)alloc((size_t)H_DIM * H_DIM * sizeof(ushort_t));
    ushort_t* Wihph = (ushort_t*)alloc((size_t)H_DIM * H3 * sizeof(ushort_t));
    ushort_t* Wihpl = (ushort_t*)alloc((size_t)H_DIM * H3 * sizeof(ushort_t));
    ushort_t* Whhph = (ushort_t*)alloc((size_t)H_DIM * H3 * sizeof(ushort_t));
    ushort_t* Whhpl = (ushort_t*)alloc((size_t)H_DIM * H3 * sizeof(ushort_t));
    // activations
    ushort_t* t_hi  = (ushort_t*)alloc((size_t)N * H_DIM * sizeof(ushort_t));
    ushort_t* t_lo  = (ushort_t*)alloc((size_t)N * H_DIM * sizeof(ushort_t));
    float* hstate   = (float*)alloc((size_t)N * H_DIM * sizeof(float));
    ushort_t* h_hi  = (ushort_t*)alloc((size_t)N * H_DIM * sizeof(ushort_t));
    ushort_t* h_lo  = (ushort_t*)alloc((size_t)N * H_DIM * sizeof(ushort_t));
    float* gi       = (float*)alloc((size_t)N * H3 * sizeof(float));
    float* gh       = (float*)alloc((size_t)N * H3 * sizeof(float));
    // aliases (sequential lifetime within a step)
    float* bufA = gh;   // conv outputs (pre-agg)
    float* bufB = gi;   // agg2 output (LN input)

    const int TB = 256;
    hipLaunchKernelGGL(init_deg_kernel, dim3((N + TB - 1) / TB), dim3(TB), 0, stream, deg, indeg, N);
    hipLaunchKernelGGL(accum_deg_kernel, dim3((E + TB - 1) / TB), dim3(TB), 0, stream, src, dst, ew, deg, indeg, E);
    hipLaunchKernelGGL(dinv_kernel, dim3((N + TB - 1) / TB), dim3(TB), 0, stream, deg, selfnorm, N);
    hipLaunchKernelGGL(edge_norm_kernel, dim3((E + TB - 1) / TB), dim3(TB), 0, stream, src, dst, ew, deg, norm, E);
    hipLaunchKernelGGL(scan_kernel, dim3(1), dim3(1024), 0, stream, indeg, offs, cursor, N);
    hipLaunchKernelGGL(csr_fill_kernel, dim3((E + TB - 1) / TB), dim3(TB), 0, stream, src, dst, norm, cursor, csr_src, csr_norm, E);

    // weight packs
    {
        int tot = (F_IN / 8) * H_DIM;
        hipLaunchKernelGGL(pack_b_kernel, dim3((tot + TB - 1) / TB), dim3(TB), 0, stream, W1, W1ph, W1pl, F_IN, H_DIM, 0);
        tot = (H_DIM / 8) * H_DIM;
        hipLaunchKernelGGL(pack_b_kernel, dim3((tot + TB - 1) / TB), dim3(TB), 0, stream, W2, W2ph, W2pl, H_DIM, H_DIM, 0);
        tot = (H_DIM / 8) * H3;
        hipLaunchKernelGGL(pack_b_kernel, dim3((tot + TB - 1) / TB), dim3(TB), 0, stream, Wih, Wihph, Wihpl, H_DIM, H3, 1);
        hipLaunchKernelGGL(pack_b_kernel, dim3((tot + TB - 1) / TB), dim3(TB), 0, stream, Whh, Whhph, Whhpl, H_DIM, H3, 1);
    }

    hipMemsetAsync(hstate, 0, (size_t)N * H_DIM * sizeof(float), stream);
    hipMemsetAsync(h_hi, 0, (size_t)N * H_DIM * sizeof(ushort_t), stream);
    hipMemsetAsync(h_lo, 0, (size_t)N * H_DIM * sizeof(ushort_t), stream);

    const int GM = (N + 127) / 128;  // 157
    dim3 gb(256);
    dim3 g_conv(GM, H_DIM / 128);    // (157, 2)
    dim3 g_gru(GM, H3 / 128);        // (157, 6)

    for (int t = 0; t < T_STEPS; t++) {
        const float* xt = x + (size_t)t * N * F_IN;
        hipLaunchKernelGGL(split_kernel, dim3((N * F_IN + TB - 1) / TB), dim3(TB), 0, stream,
                           xt, xs_hi, xs_lo, N * F_IN);
        // conv1: bufA = xt @ W1
        hipLaunchKernelGGL(gemm_split_kernel, g_conv, gb, 0, stream,
                           xs_hi, xs_lo, W1ph, W1pl, (const float*)nullptr, bufA, N, H_DIM, F_IN);
        // agg + b1 + leaky -> t_hi/t_lo (bf16 split)
        hipLaunchKernelGGL((gcn_agg_kernel<true, true>), dim3(N), dim3(H_DIM), 0, stream,
                           bufA, offs, csr_src, csr_norm, selfnorm, b1, (float*)nullptr, t_hi, t_lo);
        // conv2: bufA = t @ W2
        hipLaunchKernelGGL(gemm_split_kernel, g_conv, gb, 0, stream,
                           t_hi, t_lo, W2ph, W2pl, (const float*)nullptr, bufA, N, H_DIM, H_DIM);
        // agg + b2 -> bufB (fp32)
        hipLaunchKernelGGL((gcn_agg_kernel<false, false>), dim3(N), dim3(H_DIM), 0, stream,
                           bufA, offs, csr_src, csr_norm, selfnorm, b2, bufB, (ushort_t*)nullptr, (ushort_t*)nullptr);
        // layernorm -> t_hi/t_lo (enc split)
        hipLaunchKernelGGL(layernorm_kernel, dim3(N), dim3(H_DIM), 0, stream, bufB, lnw, lnb, t_hi, t_lo);
        // gi = enc @ Wih^T + bih   (overwrites bufB region — LN already consumed)
        hipLaunchKernelGGL(gemm_split_kernel, g_gru, gb, 0, stream,
                           t_hi, t_lo, Wihph, Wihpl, bih, gi, N, H3, H_DIM);
        // gh = h @ Whh^T + bhh     (overwrites bufA region — dead)
        hipLaunchKernelGGL(gemm_split_kernel, g_gru, gb, 0, stream,
                           h_hi, h_lo, Whhph, Whhpl, bhh, gh, N, H3, H_DIM);
        hipLaunchKernelGGL(gru_pw_kernel, dim3((N * H_DIM + TB - 1) / TB), dim3(TB), 0, stream,
                           gi, gh, hstate, h_hi, h_lo);
    }

    hipLaunchKernelGGL(fc_kernel, dim3((N + 3) / 4), dim3(256), 0, stream, hstate, Wfc, bfc, (float*)d_out, N);
}

// Round 3
// 7132.907 us; speedup vs baseline: 1.5619x; 1.1642x over previous
//
#include <hip/hip_runtime.h>
#include <math.h>

// Problem constants (fixed by reference)
#define T_STEPS 24
#define N_NODES 20000
#define F_IN 64
#define H_DIM 256
#define H3 (3 * H_DIM)

typedef unsigned short ushort_t;
using bf16x8 = __attribute__((ext_vector_type(8))) __bf16;
using f32x4  = __attribute__((ext_vector_type(4))) float;
using f16x2  = __attribute__((ext_vector_type(2))) _Float16;

// ---------------------------------------------------------------------------
// bf16 split helpers (RNE)
// ---------------------------------------------------------------------------
__device__ __forceinline__ unsigned short f2bf(float x) {
    unsigned int u = __float_as_uint(x);
    u += 0x7fff + ((u >> 16) & 1);
    return (unsigned short)(u >> 16);
}
__device__ __forceinline__ float bf2f(unsigned short h) {
    return __uint_as_float(((unsigned int)h) << 16);
}
__device__ __forceinline__ void split2(float x, unsigned short& hi, unsigned short& lo) {
    unsigned short h = f2bf(x);
    hi = h;
    lo = f2bf(x - bf2f(h));
}

__device__ __forceinline__ void gload_lds16(const void* g, void* l) {
    __builtin_amdgcn_global_load_lds(
        (const __attribute__((address_space(1))) void*)(uintptr_t)g,
        (__attribute__((address_space(3))) void*)l, 16, 0, 0);
}

// ---------------------------------------------------------------------------
// Norm / CSR build kernels
// ---------------------------------------------------------------------------
__global__ void init_deg_kernel(float* deg, int* indeg, int n) {
    int i = blockIdx.x * blockDim.x + threadIdx.x;
    if (i < n) { deg[i] = 1.0f; indeg[i] = 0; }
}

__global__ void accum_deg_kernel(const int* __restrict__ src, const int* __restrict__ dst,
                                 const float* __restrict__ ew, float* deg, int* indeg, int E) {
    int e = blockIdx.x * blockDim.x + threadIdx.x;
    if (e < E) {
        atomicAdd(&deg[dst[e]], ew[e]);
        atomicAdd(&indeg[dst[e]], 1);
    }
}

__global__ void dinv_kernel(float* deg, float* selfnorm, int n) {
    int i = blockIdx.x * blockDim.x + threadIdx.x;
    if (i < n) {
        float d = deg[i];
        float di = (d > 0.0f) ? rsqrtf(d) : 0.0f;
        deg[i] = di;
        selfnorm[i] = di * di;
    }
}

__global__ void edge_norm_kernel(const int* __restrict__ src, const int* __restrict__ dst,
                                 const float* __restrict__ ew, const float* __restrict__ dinv,
                                 float* norm, int E) {
    int e = blockIdx.x * blockDim.x + threadIdx.x;
    if (e < E) norm[e] = dinv[src[e]] * ew[e] * dinv[dst[e]];
}

__global__ void scan_kernel(const int* __restrict__ indeg, int* offs, int* cursor, int N) {
    __shared__ int part[1024];
    int t = threadIdx.x;
    const int CH = (N + 1023) / 1024;
    int s = 0;
    for (int i = 0; i < CH; i++) {
        int idx = t * CH + i;
        if (idx < N) s += indeg[idx];
    }
    part[t] = s;
    __syncthreads();
    for (int off = 1; off < 1024; off <<= 1) {
        int v = (t >= off) ? part[t - off] : 0;
        __syncthreads();
        part[t] += v;
        __syncthreads();
    }
    int base = (t == 0) ? 0 : part[t - 1];
    for (int i = 0; i < CH; i++) {
        int idx = t * CH + i;
        if (idx < N) {
            offs[idx] = base;
            cursor[idx] = base;
            base += indeg[idx];
        }
    }
    if (t == 0) offs[N] = part[1023];
}

__global__ void csr_fill_kernel(const int* __restrict__ src, const int* __restrict__ dst,
                                const float* __restrict__ norm, int* cursor,
                                int* csr_src, float* csr_norm, int E) {
    int e = blockIdx.x * blockDim.x + threadIdx.x;
    if (e < E) {
        int d = dst[e];
        int pos = atomicAdd(&cursor[d], 1);
        csr_src[pos] = src[e];
        csr_norm[pos] = norm[e];
    }
}

// ---------------------------------------------------------------------------
// Weight pack: P[kk][n][j] (hi/lo bf16) for j=0..7, kk=k/8.
// trans=0: B = W [K,N] row-major.  trans=1: B = W^T with W [N,K] row-major.
// ---------------------------------------------------------------------------
__global__ void pack_b_kernel(const float* __restrict__ W, ushort_t* __restrict__ Phi,
                              ushort_t* __restrict__ Plo, int K, int Nn, int trans) {
    int idx = blockIdx.x * blockDim.x + threadIdx.x;
    int total = (K >> 3) * Nn;
    if (idx >= total) return;
    int kk = idx / Nn, n = idx - kk * Nn;
    size_t o = (size_t)idx * 8;
    for (int j = 0; j < 8; ++j) {
        float v = trans ? W[(size_t)n * K + kk * 8 + j] : W[(size_t)(kk * 8 + j) * Nn + n];
        ushort_t h, l;
        split2(v, h, l);
        Phi[o + j] = h;
        Plo[o + j] = l;
    }
}

// fp32 -> fp16
__global__ void tofp16_kernel(const float* __restrict__ in, _Float16* __restrict__ out, int n) {
    int i = blockIdx.x * blockDim.x + threadIdx.x;
    if (i < n) out[i] = (_Float16)in[i];
}

// ---------------------------------------------------------------------------
// agg1: out[n][f] = selfnorm[n]*x[n][f] + sum_e norm*x[src][f], f in [0,64)
// fp16 gather, fp32 accum, bf16 hi/lo split output. One wave per node.
// ---------------------------------------------------------------------------
__global__ void agg1_kernel(const _Float16* __restrict__ xs, const int* __restrict__ offs,
                            const int* __restrict__ csr_src, const float* __restrict__ csr_norm,
                            const float* __restrict__ selfnorm,
                            ushort_t* __restrict__ outh, ushort_t* __restrict__ outl, int N) {
    int n = blockIdx.x * 4 + (threadIdx.x >> 6);
    int lane = threadIdx.x & 63;
    if (n >= N) return;
    float acc = selfnorm[n] * (float)xs[(size_t)n * F_IN + lane];
    int e0 = offs[n], e1 = offs[n + 1];
    for (int e = e0; e < e1; e++) {
        int s = csr_src[e];
        float w = csr_norm[e];
        acc = fmaf(w, (float)xs[(size_t)s * F_IN + lane], acc);
    }
    ushort_t h, l;
    split2(acc, h, l);
    size_t o = (size_t)n * F_IN + lane;
    outh[o] = h;
    outl[o] = l;
}

// ---------------------------------------------------------------------------
// agg2: 256-dim fp16 gather, 2 nodes per block (128 threads each, half2/lane).
// bf16 hi/lo split output.
// ---------------------------------------------------------------------------
__global__ void agg2_kernel(const _Float16* __restrict__ hs, const int* __restrict__ offs,
                            const int* __restrict__ csr_src, const float* __restrict__ csr_norm,
                            const float* __restrict__ selfnorm,
                            ushort_t* __restrict__ outh, ushort_t* __restrict__ outl, int N) {
    int n = blockIdx.x * 2 + (threadIdx.x >> 7);
    int t = threadIdx.x & 127;           // handles features 2t, 2t+1
    if (n >= N) return;
    f16x2 own = *(const f16x2*)&hs[(size_t)n * H_DIM + 2 * t];
    float sn = selfnorm[n];
    float a0 = sn * (float)own[0];
    float a1 = sn * (float)own[1];
    int e0 = offs[n], e1 = offs[n + 1];
    for (int e = e0; e < e1; e++) {
        int s = csr_src[e];
        float w = csr_norm[e];
        f16x2 v = *(const f16x2*)&hs[(size_t)s * H_DIM + 2 * t];
        a0 = fmaf(w, (float)v[0], a0);
        a1 = fmaf(w, (float)v[1], a1);
    }
    size_t o = (size_t)n * H_DIM + 2 * t;
    ushort_t h, l;
    split2(a0, h, l);
    outh[o] = h; outl[o] = l;
    split2(a1, h, l);
    outh[o + 1] = h; outl[o + 1] = l;
}

// ---------------------------------------------------------------------------
// Split-bf16 MFMA GEMM: C[M,Nn] = (Ahi+Alo)[M,K] @ (Bhi+Blo)[K,Nn] (+bias)
// 128x128 tile, BK=32, 256 threads = 4 waves (2x2), 16x16x32 bf16 MFMA.
// EPI 0: fp32 out (+bias). EPI 1: bias + leaky -> fp16 out.
// ---------------------------------------------------------------------------
template <int EPI>
__global__ __launch_bounds__(256, 2)
void gemm_split_kernel(const ushort_t* __restrict__ Ahi, const ushort_t* __restrict__ Alo,
                       const ushort_t* __restrict__ Bhi, const ushort_t* __restrict__ Blo,
                       const float* __restrict__ bias, float* __restrict__ C,
                       _Float16* __restrict__ C16, int M, int Nn, int K) {
    __shared__ ushort_t Ah[4][128][8];
    __shared__ ushort_t Al[4][128][8];
    __shared__ ushort_t Bh[4][128][8];
    __shared__ ushort_t Bl[4][128][8];

    const int tid = threadIdx.x;
    const int wave = tid >> 6, lane = tid & 63;
    const int bm = blockIdx.x * 128, bn = blockIdx.y * 128;
    const int wm = (wave >> 1) * 64, wn = (wave & 1) * 64;
    const int kq = lane >> 4, r = lane & 15;

    f32x4 acc[4][4];
#pragma unroll
    for (int i = 0; i < 4; ++i)
#pragma unroll
        for (int j = 0; j < 4; ++j) acc[i][j] = (f32x4){0.f, 0.f, 0.f, 0.f};

    for (int k0 = 0; k0 < K; k0 += 32) {
        __syncthreads();
        const int kb = k0 >> 3;
#pragma unroll
        for (int it = 0; it < 2; ++it) {
            int c = it * 256 + tid;
            int kk = c >> 7, idx = c & 127;
            int row = bm + idx;
            if (row >= M) row = M - 1;
            size_t aoff = (size_t)row * K + k0 + kk * 8;
            size_t boff = ((size_t)(kb + kk) * Nn + bn + idx) * 8;
            int lbase = (it * 256 + wave * 64) * 8;
            gload_lds16(Ahi + aoff, &Ah[0][0][0] + lbase);
            gload_lds16(Alo + aoff, &Al[0][0][0] + lbase);
            gload_lds16(Bhi + boff, &Bh[0][0][0] + lbase);
            gload_lds16(Blo + boff, &Bl[0][0][0] + lbase);
        }
        __syncthreads();

        bf16x8 ah[4], al[4], bh[4], bl[4];
#pragma unroll
        for (int f = 0; f < 4; ++f) {
            ah[f] = *(const bf16x8*)&Ah[kq][wm + f * 16 + r][0];
            al[f] = *(const bf16x8*)&Al[kq][wm + f * 16 + r][0];
            bh[f] = *(const bf16x8*)&Bh[kq][wn + f * 16 + r][0];
            bl[f] = *(const bf16x8*)&Bl[kq][wn + f * 16 + r][0];
        }
#pragma unroll
        for (int i = 0; i < 4; ++i)
#pragma unroll
            for (int j = 0; j < 4; ++j) {
                acc[i][j] = __builtin_amdgcn_mfma_f32_16x16x32_bf16(ah[i], bh[j], acc[i][j], 0, 0, 0);
                acc[i][j] = __builtin_amdgcn_mfma_f32_16x16x32_bf16(ah[i], bl[j], acc[i][j], 0, 0, 0);
                acc[i][j] = __builtin_amdgcn_mfma_f32_16x16x32_bf16(al[i], bh[j], acc[i][j], 0, 0, 0);
            }
    }

    // C/D layout: col = lane&15, row = (lane>>4)*4 + reg  [m89]
#pragma unroll
    for (int j = 0; j < 4; ++j) {
        int col = bn + wn + j * 16 + r;
        float bv = bias ? bias[col] : 0.0f;
#pragma unroll
        for (int i = 0; i < 4; ++i) {
#pragma unroll
            for (int q = 0; q < 4; ++q) {
                int row = bm + wm + i * 16 + kq * 4 + q;
                if (row < M) {
                    float v = acc[i][j][q] + bv;
                    if (EPI == 1) {
                        v = (v >= 0.0f) ? v : 0.01f * v;
                        C16[(size_t)row * Nn + col] = (_Float16)v;
                    } else {
                        C[(size_t)row * Nn + col] = v;
                    }
                }
            }
        }
    }
}

// ---------------------------------------------------------------------------
// LayerNorm over 256 features -> bf16 hi/lo output
// ---------------------------------------------------------------------------
__global__ void layernorm_kernel(const float* __restrict__ in, const float* __restrict__ w,
                                 const float* __restrict__ b, ushort_t* __restrict__ outh,
                                 ushort_t* __restrict__ outl) {
    int n = blockIdx.x;
    int f = threadIdx.x;
    float v = in[(size_t)n * H_DIM + f];
    float s = v, s2 = v * v;
#pragma unroll
    for (int o = 32; o > 0; o >>= 1) {
        s += __shfl_down(s, o, 64);
        s2 += __shfl_down(s2, o, 64);
    }
    __shared__ float ps[4], ps2[4];
    int wid = f >> 6;
    if ((f & 63) == 0) { ps[wid] = s; ps2[wid] = s2; }
    __syncthreads();
    float S = ps[0] + ps[1] + ps[2] + ps[3];
    float S2 = ps2[0] + ps2[1] + ps2[2] + ps2[3];
    float mu = S * (1.0f / H_DIM);
    float var = S2 * (1.0f / H_DIM) - mu * mu;
    float rstd = rsqrtf(var + 1e-5f);
    float outv = (v - mu) * rstd * w[f] + b[f];
    size_t o = (size_t)n * H_DIM + f;
    ushort_t hh, ll;
    split2(outv, hh, ll);
    outh[o] = hh;
    outl[o] = ll;
}

// ---------------------------------------------------------------------------
// GRU pointwise; writes h (fp32) and its bf16 hi/lo split.
// ---------------------------------------------------------------------------
__device__ __forceinline__ float sigmoidf_(float x) { return 1.0f / (1.0f + expf(-x)); }

__global__ void gru_pw_kernel(const float* __restrict__ gi, const float* __restrict__ gh,
                              float* __restrict__ h, ushort_t* __restrict__ hhi,
                              ushort_t* __restrict__ hlo) {
    int idx = blockIdx.x * blockDim.x + threadIdx.x;
    if (idx >= N_NODES * H_DIM) return;
    int n = idx >> 8;
    int j = idx & (H_DIM - 1);
    const float* gin = gi + (size_t)n * H3;
    const float* ghn = gh + (size_t)n * H3;
    float r = sigmoidf_(gin[j] + ghn[j]);
    float z = sigmoidf_(gin[H_DIM + j] + ghn[H_DIM + j]);
    float nn = tanhf(gin[2 * H_DIM + j] + r * ghn[2 * H_DIM + j]);
    float hp = h[idx];
    float hv = (1.0f - z) * nn + z * hp;
    h[idx] = hv;
    ushort_t hh, ll;
    split2(hv, hh, ll);
    hhi[idx] = hh;
    hlo[idx] = ll;
}

// ---------------------------------------------------------------------------
// fc: out[n] = dot(h[n,:], Wfc[0,:]) + bfc
// ---------------------------------------------------------------------------
__global__ void fc_kernel(const float* __restrict__ h, const float* __restrict__ Wfc,
                          const float* __restrict__ bfc, float* __restrict__ out, int N) {
    int n = blockIdx.x * 4 + (threadIdx.x >> 6);
    int lane = threadIdx.x & 63;
    if (n >= N) return;
    float4 hv = *(const float4*)&h[(size_t)n * H_DIM + lane * 4];
    float4 wv = *(const float4*)&Wfc[lane * 4];
    float acc = hv.x * wv.x + hv.y * wv.y + hv.z * wv.z + hv.w * wv.w;
#pragma unroll
    for (int o = 32; o > 0; o >>= 1) acc += __shfl_down(acc, o, 64);
    if (lane == 0) out[n] = acc + bfc[0];
}

// ---------------------------------------------------------------------------
// Launch
// ---------------------------------------------------------------------------
extern "C" void kernel_launch(void* const* d_in, const int* in_sizes, int n_in,
                              void* d_out, int out_size, void* d_ws, size_t ws_size,
                              hipStream_t stream) {
    const float* x   = (const float*)d_in[0];
    const int* eidx  = (const int*)d_in[1];
    const float* ew  = (const float*)d_in[2];
    const float* W1  = (const float*)d_in[3];
    const float* b1  = (const float*)d_in[4];
    const float* W2  = (const float*)d_in[5];
    const float* b2  = (const float*)d_in[6];
    const float* lnw = (const float*)d_in[7];
    const float* lnb = (const float*)d_in[8];
    const float* Wih = (const float*)d_in[9];
    const float* Whh = (const float*)d_in[10];
    const float* bih = (const float*)d_in[11];
    const float* bhh = (const float*)d_in[12];
    const float* Wfc = (const float*)d_in[13];
    const float* bfc = (const float*)d_in[14];

    const int E = in_sizes[2];
    const int N = N_NODES;
    const int* src = eidx;
    const int* dst = eidx + E;

    uintptr_t p = (uintptr_t)d_ws;
    auto alloc = [&](size_t bytes) -> void* {
        p = (p + 255) & ~(uintptr_t)255;
        void* r = (void*)p;
        p += bytes;
        return r;
    };
    // CSR / norm
    float* deg      = (float*)alloc(N * sizeof(float));
    float* selfnorm = (float*)alloc(N * sizeof(float));
    float* norm     = (float*)alloc(E * sizeof(float));
    int* indeg      = (int*)alloc(N * sizeof(int));
    int* offs       = (int*)alloc((N + 1) * sizeof(int));
    int* cursor     = (int*)alloc(N * sizeof(int));
    int* csr_src    = (int*)alloc(E * sizeof(int));
    float* csr_norm = (float*)alloc(E * sizeof(float));
    // weight packs
    ushort_t* W1ph  = (ushort_t*)alloc((size_t)F_IN * H_DIM * sizeof(ushort_t));
    ushort_t* W1pl  = (ushort_t*)alloc((size_t)F_IN * H_DIM * sizeof(ushort_t));
    ushort_t* W2ph  = (ushort_t*)alloc((size_t)H_DIM * H_DIM * sizeof(ushort_t));
    ushort_t* W2pl  = (ushort_t*)alloc((size_t)H_DIM * H_DIM * sizeof(ushort_t));
    ushort_t* Wihph = (ushort_t*)alloc((size_t)H_DIM * H3 * sizeof(ushort_t));
    ushort_t* Wihpl = (ushort_t*)alloc((size_t)H_DIM * H3 * sizeof(ushort_t));
    ushort_t* Whhph = (ushort_t*)alloc((size_t)H_DIM * H3 * sizeof(ushort_t));
    ushort_t* Whhpl = (ushort_t*)alloc((size_t)H_DIM * H3 * sizeof(ushort_t));
    // activations
    _Float16* xs16  = (_Float16*)alloc((size_t)N * F_IN * sizeof(_Float16));
    ushort_t* a1_hi = (ushort_t*)alloc((size_t)N * F_IN * sizeof(ushort_t));
    ushort_t* a1_lo = (ushort_t*)alloc((size_t)N * F_IN * sizeof(ushort_t));
    _Float16* h1_16 = (_Float16*)alloc((size_t)N * H_DIM * sizeof(_Float16));
    ushort_t* a2_hi = (ushort_t*)alloc((size_t)N * H_DIM * sizeof(ushort_t));
    ushort_t* a2_lo = (ushort_t*)alloc((size_t)N * H_DIM * sizeof(ushort_t));
    float* bufB     = (float*)alloc((size_t)N * H_DIM * sizeof(float));
    ushort_t* e_hi  = (ushort_t*)alloc((size_t)N * H_DIM * sizeof(ushort_t));
    ushort_t* e_lo  = (ushort_t*)alloc((size_t)N * H_DIM * sizeof(ushort_t));
    float* hstate   = (float*)alloc((size_t)N * H_DIM * sizeof(float));
    ushort_t* h_hi  = (ushort_t*)alloc((size_t)N * H_DIM * sizeof(ushort_t));
    ushort_t* h_lo  = (ushort_t*)alloc((size_t)N * H_DIM * sizeof(ushort_t));
    float* gi       = (float*)alloc((size_t)N * H3 * sizeof(float));
    float* gh       = (float*)alloc((size_t)N * H3 * sizeof(float));

    const int TB = 256;
    hipLaunchKernelGGL(init_deg_kernel, dim3((N + TB - 1) / TB), dim3(TB), 0, stream, deg, indeg, N);
    hipLaunchKernelGGL(accum_deg_kernel, dim3((E + TB - 1) / TB), dim3(TB), 0, stream, src, dst, ew, deg, indeg, E);
    hipLaunchKernelGGL(dinv_kernel, dim3((N + TB - 1) / TB), dim3(TB), 0, stream, deg, selfnorm, N);
    hipLaunchKernelGGL(edge_norm_kernel, dim3((E + TB - 1) / TB), dim3(TB), 0, stream, src, dst, ew, deg, norm, E);
    hipLaunchKernelGGL(scan_kernel, dim3(1), dim3(1024), 0, stream, indeg, offs, cursor, N);
    hipLaunchKernelGGL(csr_fill_kernel, dim3((E + TB - 1) / TB), dim3(TB), 0, stream, src, dst, norm, cursor, csr_src, csr_norm, E);

    // weight packs
    {
        int tot = (F_IN / 8) * H_DIM;
        hipLaunchKernelGGL(pack_b_kernel, dim3((tot + TB - 1) / TB), dim3(TB), 0, stream, W1, W1ph, W1pl, F_IN, H_DIM, 0);
        tot = (H_DIM / 8) * H_DIM;
        hipLaunchKernelGGL(pack_b_kernel, dim3((tot + TB - 1) / TB), dim3(TB), 0, stream, W2, W2ph, W2pl, H_DIM, H_DIM, 0);
        tot = (H_DIM / 8) * H3;
        hipLaunchKernelGGL(pack_b_kernel, dim3((tot + TB - 1) / TB), dim3(TB), 0, stream, Wih, Wihph, Wihpl, H_DIM, H3, 1);
        hipLaunchKernelGGL(pack_b_kernel, dim3((tot + TB - 1) / TB), dim3(TB), 0, stream, Whh, Whhph, Whhpl, H_DIM, H3, 1);
    }

    hipMemsetAsync(hstate, 0, (size_t)N * H_DIM * sizeof(float), stream);
    hipMemsetAsync(h_hi, 0, (size_t)N * H_DIM * sizeof(ushort_t), stream);
    hipMemsetAsync(h_lo, 0, (size_t)N * H_DIM * sizeof(ushort_t), stream);

    const int GM = (N + 127) / 128;  // 157
    dim3 gb(256);
    dim3 g_conv(GM, H_DIM / 128);    // (157, 2)
    dim3 g_gru(GM, H3 / 128);        // (157, 6)

    for (int t = 0; t < T_STEPS; t++) {
        const float* xt = x + (size_t)t * N * F_IN;
        // x -> fp16
        hipLaunchKernelGGL(tofp16_kernel, dim3((N * F_IN + TB - 1) / TB), dim3(TB), 0, stream,
                           xt, xs16, N * F_IN);
        // agg1: a1 = A @ x   (64-dim gather, exact commute)
        hipLaunchKernelGGL(agg1_kernel, dim3((N + 3) / 4), dim3(256), 0, stream,
                           xs16, offs, csr_src, csr_norm, selfnorm, a1_hi, a1_lo, N);
        // conv1: h1 = leaky(a1 @ W1 + b1) -> fp16
        hipLaunchKernelGGL((gemm_split_kernel<1>), g_conv, gb, 0, stream,
                           a1_hi, a1_lo, W1ph, W1pl, b1, (float*)nullptr, h1_16, N, H_DIM, F_IN);
        // agg2: a2 = A @ h1  (256-dim fp16 gather, exact commute)
        hipLaunchKernelGGL(agg2_kernel, dim3((N + 1) / 2), dim3(256), 0, stream,
                           h1_16, offs, csr_src, csr_norm, selfnorm, a2_hi, a2_lo, N);
        // conv2: bufB = a2 @ W2 + b2
        hipLaunchKernelGGL((gemm_split_kernel<0>), g_conv, gb, 0, stream,
                           a2_hi, a2_lo, W2ph, W2pl, b2, bufB, (_Float16*)nullptr, N, H_DIM, H_DIM);
        // layernorm -> enc hi/lo
        hipLaunchKernelGGL(layernorm_kernel, dim3(N), dim3(H_DIM), 0, stream, bufB, lnw, lnb, e_hi, e_lo);
        // gi = enc @ Wih^T + bih
        hipLaunchKernelGGL((gemm_split_kernel<0>), g_gru, gb, 0, stream,
                           e_hi, e_lo, Wihph, Wihpl, bih, gi, (_Float16*)nullptr, N, H3, H_DIM);
        // gh = h @ Whh^T + bhh
        hipLaunchKernelGGL((gemm_split_kernel<0>), g_gru, gb, 0, stream,
                           h_hi, h_lo, Whhph, Whhpl, bhh, gh, (_Float16*)nullptr, N, H3, H_DIM);
        hipLaunchKernelGGL(gru_pw_kernel, dim3((N * H_DIM + TB - 1) / TB), dim3(TB), 0, stream,
                           gi, gh, hstate, h_hi, h_lo);
    }

    hipLaunchKernelGGL(fc_kernel, dim3((N + 3) / 4), dim3(256), 0, stream, hstate, Wfc, bfc, (float*)d_out, N);
}

// Round 4
// 5524.343 us; speedup vs baseline: 2.0167x; 1.2912x over previous
//
#include <hip/hip_runtime.h>
#include <math.h>

// Problem constants (fixed by reference)
#define T_STEPS 24
#define N_NODES 20000
#define F_IN 64
#define H_DIM 256
#define H3 (3 * H_DIM)

using f16x8 = __attribute__((ext_vector_type(8))) _Float16;
using f16x4 = __attribute__((ext_vector_type(4))) _Float16;
using f16x2 = __attribute__((ext_vector_type(2))) _Float16;
using f32x4 = __attribute__((ext_vector_type(4))) float;

__device__ __forceinline__ void gload_lds16(const void* g, void* l) {
    __builtin_amdgcn_global_load_lds(
        (const __attribute__((address_space(1))) void*)(uintptr_t)g,
        (__attribute__((address_space(3))) void*)l, 16, 0, 0);
}

// ---------------------------------------------------------------------------
// Norm / CSR build kernels
// ---------------------------------------------------------------------------
__global__ void init_deg_kernel(float* deg, int* indeg, int n) {
    int i = blockIdx.x * blockDim.x + threadIdx.x;
    if (i < n) { deg[i] = 1.0f; indeg[i] = 0; }
}

__global__ void accum_deg_kernel(const int* __restrict__ src, const int* __restrict__ dst,
                                 const float* __restrict__ ew, float* deg, int* indeg, int E) {
    int e = blockIdx.x * blockDim.x + threadIdx.x;
    if (e < E) {
        atomicAdd(&deg[dst[e]], ew[e]);
        atomicAdd(&indeg[dst[e]], 1);
    }
}

__global__ void dinv_kernel(float* deg, float* selfnorm, int n) {
    int i = blockIdx.x * blockDim.x + threadIdx.x;
    if (i < n) {
        float d = deg[i];
        float di = (d > 0.0f) ? rsqrtf(d) : 0.0f;
        deg[i] = di;
        selfnorm[i] = di * di;
    }
}

__global__ void edge_norm_kernel(const int* __restrict__ src, const int* __restrict__ dst,
                                 const float* __restrict__ ew, const float* __restrict__ dinv,
                                 float* norm, int E) {
    int e = blockIdx.x * blockDim.x + threadIdx.x;
    if (e < E) norm[e] = dinv[src[e]] * ew[e] * dinv[dst[e]];
}

__global__ void scan_kernel(const int* __restrict__ indeg, int* offs, int* cursor, int N) {
    __shared__ int part[1024];
    int t = threadIdx.x;
    const int CH = (N + 1023) / 1024;
    int s = 0;
    for (int i = 0; i < CH; i++) {
        int idx = t * CH + i;
        if (idx < N) s += indeg[idx];
    }
    part[t] = s;
    __syncthreads();
    for (int off = 1; off < 1024; off <<= 1) {
        int v = (t >= off) ? part[t - off] : 0;
        __syncthreads();
        part[t] += v;
        __syncthreads();
    }
    int base = (t == 0) ? 0 : part[t - 1];
    for (int i = 0; i < CH; i++) {
        int idx = t * CH + i;
        if (idx < N) {
            offs[idx] = base;
            cursor[idx] = base;
            base += indeg[idx];
        }
    }
    if (t == 0) offs[N] = part[1023];
}

__global__ void csr_fill_kernel(const int* __restrict__ src, const int* __restrict__ dst,
                                const float* __restrict__ norm, int* cursor,
                                int* csr_src, float* csr_norm, int E) {
    int e = blockIdx.x * blockDim.x + threadIdx.x;
    if (e < E) {
        int d = dst[e];
        int pos = atomicAdd(&cursor[d], 1);
        csr_src[pos] = src[e];
        csr_norm[pos] = norm[e];
    }
}

// ---------------------------------------------------------------------------
// Weight pack (fp16): P[kk][n][j], j=0..7, kk=k/8.
// trans=0: B = W [K,N] row-major.  trans=1: B = W^T with W [N,K] row-major.
// ---------------------------------------------------------------------------
__global__ void pack_b16_kernel(const float* __restrict__ W, _Float16* __restrict__ P,
                                int K, int Nn, int trans) {
    int idx = blockIdx.x * blockDim.x + threadIdx.x;
    int total = (K >> 3) * Nn;
    if (idx >= total) return;
    int kk = idx / Nn, n = idx - kk * Nn;
    size_t o = (size_t)idx * 8;
    for (int j = 0; j < 8; ++j) {
        float v = trans ? W[(size_t)n * K + kk * 8 + j] : W[(size_t)(kk * 8 + j) * Nn + n];
        P[o + j] = (_Float16)v;
    }
}

// fp32 -> fp16 (vectorized x4)
__global__ void tofp16_kernel(const float* __restrict__ in, _Float16* __restrict__ out, int n4) {
    int i = blockIdx.x * blockDim.x + threadIdx.x;
    if (i < n4) {
        float4 v = ((const float4*)in)[i];
        f16x4 o = { (_Float16)v.x, (_Float16)v.y, (_Float16)v.z, (_Float16)v.w };
        ((f16x4*)out)[i] = o;
    }
}

// ---------------------------------------------------------------------------
// agg1: out[n][f] = selfnorm[n]*x[n][f] + sum_e norm*x[src][f], f in [0,64)
// fp16 gather, fp32 accum, fp16 out. One wave per node.
// ---------------------------------------------------------------------------
__global__ void agg1_kernel(const _Float16* __restrict__ xs, const int* __restrict__ offs,
                            const int* __restrict__ csr_src, const float* __restrict__ csr_norm,
                            const float* __restrict__ selfnorm,
                            _Float16* __restrict__ out, int N) {
    int n = blockIdx.x * 4 + (threadIdx.x >> 6);
    int lane = threadIdx.x & 63;
    if (n >= N) return;
    float acc = selfnorm[n] * (float)xs[(size_t)n * F_IN + lane];
    int e0 = offs[n], e1 = offs[n + 1];
    for (int e = e0; e < e1; e++) {
        int s = csr_src[e];
        float w = csr_norm[e];
        acc = fmaf(w, (float)xs[(size_t)s * F_IN + lane], acc);
    }
    out[(size_t)n * F_IN + lane] = (_Float16)acc;
}

// ---------------------------------------------------------------------------
// agg2: 256-dim fp16 gather, 2 nodes per block (128 threads each, f16x2/lane).
// fp16 out.
// ---------------------------------------------------------------------------
__global__ void agg2_kernel(const _Float16* __restrict__ hs, const int* __restrict__ offs,
                            const int* __restrict__ csr_src, const float* __restrict__ csr_norm,
                            const float* __restrict__ selfnorm,
                            _Float16* __restrict__ out, int N) {
    int n = blockIdx.x * 2 + (threadIdx.x >> 7);
    int t = threadIdx.x & 127;
    if (n >= N) return;
    f16x2 own = *(const f16x2*)&hs[(size_t)n * H_DIM + 2 * t];
    float sn = selfnorm[n];
    float a0 = sn * (float)own[0];
    float a1 = sn * (float)own[1];
    int e0 = offs[n], e1 = offs[n + 1];
    for (int e = e0; e < e1; e++) {
        int s = csr_src[e];
        float w = csr_norm[e];
        f16x2 v = *(const f16x2*)&hs[(size_t)s * H_DIM + 2 * t];
        a0 = fmaf(w, (float)v[0], a0);
        a1 = fmaf(w, (float)v[1], a1);
    }
    f16x2 o = { (_Float16)a0, (_Float16)a1 };
    *(f16x2*)&out[(size_t)n * H_DIM + 2 * t] = o;
}

// ---------------------------------------------------------------------------
// fp16 MFMA GEMM: C[M,Nn] = A[M,K] @ B[K,Nn] (+bias)
// 128x128 tile, BK=32, 256 threads = 4 waves (2x2), 16x16x32 f16 MFMA.
// EPI 0: fp32 out (+bias). EPI 1: bias + leaky -> fp16 out.
// A: row-major fp16 [M,K]. B packed: [K/8][Nn][8] fp16.
// ---------------------------------------------------------------------------
template <int EPI>
__global__ __launch_bounds__(256, 4)
void gemm_f16_kernel(const _Float16* __restrict__ A, const _Float16* __restrict__ Bp,
                     const float* __restrict__ bias, float* __restrict__ C,
                     _Float16* __restrict__ C16, int M, int Nn, int K) {
    __shared__ _Float16 As[4][128][8];
    __shared__ _Float16 Bs[4][128][8];

    const int tid = threadIdx.x;
    const int wave = tid >> 6, lane = tid & 63;
    const int bm = blockIdx.x * 128, bn = blockIdx.y * 128;
    const int wm = (wave >> 1) * 64, wn = (wave & 1) * 64;
    const int kq = lane >> 4, r = lane & 15;

    f32x4 acc[4][4];
#pragma unroll
    for (int i = 0; i < 4; ++i)
#pragma unroll
        for (int j = 0; j < 4; ++j) acc[i][j] = (f32x4){0.f, 0.f, 0.f, 0.f};

    for (int k0 = 0; k0 < K; k0 += 32) {
        __syncthreads();
        const int kb = k0 >> 3;
#pragma unroll
        for (int it = 0; it < 2; ++it) {
            int c = it * 256 + tid;          // cell 0..511: kk = c>>7, idx = c&127
            int kk = c >> 7, idx = c & 127;
            int row = bm + idx;
            if (row >= M) row = M - 1;
            size_t aoff = (size_t)row * K + k0 + kk * 8;
            size_t boff = ((size_t)(kb + kk) * Nn + bn + idx) * 8;
            int lbase = (it * 256 + wave * 64) * 8;   // fp16 units, wave-uniform
            gload_lds16(A + aoff, &As[0][0][0] + lbase);
            gload_lds16(Bp + boff, &Bs[0][0][0] + lbase);
        }
        __syncthreads();

        f16x8 a[4], b[4];
#pragma unroll
        for (int f = 0; f < 4; ++f) {
            a[f] = *(const f16x8*)&As[kq][wm + f * 16 + r][0];
            b[f] = *(const f16x8*)&Bs[kq][wn + f * 16 + r][0];
        }
#pragma unroll
        for (int i = 0; i < 4; ++i)
#pragma unroll
            for (int j = 0; j < 4; ++j)
                acc[i][j] = __builtin_amdgcn_mfma_f32_16x16x32_f16(a[i], b[j], acc[i][j], 0, 0, 0);
    }

    // C/D layout: col = lane&15, row = (lane>>4)*4 + reg  [m89]
#pragma unroll
    for (int j = 0; j < 4; ++j) {
        int col = bn + wn + j * 16 + r;
        float bv = bias ? bias[col] : 0.0f;
#pragma unroll
        for (int i = 0; i < 4; ++i) {
#pragma unroll
            for (int q = 0; q < 4; ++q) {
                int row = bm + wm + i * 16 + kq * 4 + q;
                if (row < M) {
                    float v = acc[i][j][q] + bv;
                    if (EPI == 1) {
                        v = (v >= 0.0f) ? v : 0.01f * v;
                        C16[(size_t)row * Nn + col] = (_Float16)v;
                    } else {
                        C[(size_t)row * Nn + col] = v;
                    }
                }
            }
        }
    }
}

// ---------------------------------------------------------------------------
// LayerNorm over 256 features -> fp16 output
// ---------------------------------------------------------------------------
__global__ void layernorm_kernel(const float* __restrict__ in, const float* __restrict__ w,
                                 const float* __restrict__ b, _Float16* __restrict__ out) {
    int n = blockIdx.x;
    int f = threadIdx.x;
    float v = in[(size_t)n * H_DIM + f];
    float s = v, s2 = v * v;
#pragma unroll
    for (int o = 32; o > 0; o >>= 1) {
        s += __shfl_down(s, o, 64);
        s2 += __shfl_down(s2, o, 64);
    }
    __shared__ float ps[4], ps2[4];
    int wid = f >> 6;
    if ((f & 63) == 0) { ps[wid] = s; ps2[wid] = s2; }
    __syncthreads();
    float S = ps[0] + ps[1] + ps[2] + ps[3];
    float S2 = ps2[0] + ps2[1] + ps2[2] + ps2[3];
    float mu = S * (1.0f / H_DIM);
    float var = S2 * (1.0f / H_DIM) - mu * mu;
    float rstd = rsqrtf(var + 1e-5f);
    float outv = (v - mu) * rstd * w[f] + b[f];
    out[(size_t)n * H_DIM + f] = (_Float16)outv;
}

// ---------------------------------------------------------------------------
// GRU pointwise; writes h (fp32) and fp16 copy.
// ---------------------------------------------------------------------------
__device__ __forceinline__ float sigmoidf_(float x) { return 1.0f / (1.0f + expf(-x)); }

__global__ void gru_pw_kernel(const float* __restrict__ gi, const float* __restrict__ gh,
                              float* __restrict__ h, _Float16* __restrict__ h16) {
    int idx = blockIdx.x * blockDim.x + threadIdx.x;
    if (idx >= N_NODES * H_DIM) return;
    int n = idx >> 8;
    int j = idx & (H_DIM - 1);
    const float* gin = gi + (size_t)n * H3;
    const float* ghn = gh + (size_t)n * H3;
    float r = sigmoidf_(gin[j] + ghn[j]);
    float z = sigmoidf_(gin[H_DIM + j] + ghn[H_DIM + j]);
    float nn = tanhf(gin[2 * H_DIM + j] + r * ghn[2 * H_DIM + j]);
    float hp = h[idx];
    float hv = (1.0f - z) * nn + z * hp;
    h[idx] = hv;
    h16[idx] = (_Float16)hv;
}

// ---------------------------------------------------------------------------
// fc: out[n] = dot(h[n,:], Wfc[0,:]) + bfc
// ---------------------------------------------------------------------------
__global__ void fc_kernel(const float* __restrict__ h, const float* __restrict__ Wfc,
                          const float* __restrict__ bfc, float* __restrict__ out, int N) {
    int n = blockIdx.x * 4 + (threadIdx.x >> 6);
    int lane = threadIdx.x & 63;
    if (n >= N) return;
    float4 hv = *(const float4*)&h[(size_t)n * H_DIM + lane * 4];
    float4 wv = *(const float4*)&Wfc[lane * 4];
    float acc = hv.x * wv.x + hv.y * wv.y + hv.z * wv.z + hv.w * wv.w;
#pragma unroll
    for (int o = 32; o > 0; o >>= 1) acc += __shfl_down(acc, o, 64);
    if (lane == 0) out[n] = acc + bfc[0];
}

// ---------------------------------------------------------------------------
// Launch
// ---------------------------------------------------------------------------
extern "C" void kernel_launch(void* const* d_in, const int* in_sizes, int n_in,
                              void* d_out, int out_size, void* d_ws, size_t ws_size,
                              hipStream_t stream) {
    const float* x   = (const float*)d_in[0];
    const int* eidx  = (const int*)d_in[1];
    const float* ew  = (const float*)d_in[2];
    const float* W1  = (const float*)d_in[3];
    const float* b1  = (const float*)d_in[4];
    const float* W2  = (const float*)d_in[5];
    const float* b2  = (const float*)d_in[6];
    const float* lnw = (const float*)d_in[7];
    const float* lnb = (const float*)d_in[8];
    const float* Wih = (const float*)d_in[9];
    const float* Whh = (const float*)d_in[10];
    const float* bih = (const float*)d_in[11];
    const float* bhh = (const float*)d_in[12];
    const float* Wfc = (const float*)d_in[13];
    const float* bfc = (const float*)d_in[14];

    const int E = in_sizes[2];
    const int N = N_NODES;
    const int* src = eidx;
    const int* dst = eidx + E;

    uintptr_t p = (uintptr_t)d_ws;
    auto alloc = [&](size_t bytes) -> void* {
        p = (p + 255) & ~(uintptr_t)255;
        void* r = (void*)p;
        p += bytes;
        return r;
    };
    // CSR / norm
    float* deg      = (float*)alloc(N * sizeof(float));
    float* selfnorm = (float*)alloc(N * sizeof(float));
    float* norm     = (float*)alloc(E * sizeof(float));
    int* indeg      = (int*)alloc(N * sizeof(int));
    int* offs       = (int*)alloc((N + 1) * sizeof(int));
    int* cursor     = (int*)alloc(N * sizeof(int));
    int* csr_src    = (int*)alloc(E * sizeof(int));
    float* csr_norm = (float*)alloc(E * sizeof(float));
    // packed fp16 weights
    _Float16* W1p   = (_Float16*)alloc((size_t)F_IN * H_DIM * sizeof(_Float16));
    _Float16* W2p   = (_Float16*)alloc((size_t)H_DIM * H_DIM * sizeof(_Float16));
    _Float16* Wihp  = (_Float16*)alloc((size_t)H_DIM * H3 * sizeof(_Float16));
    _Float16* Whhp  = (_Float16*)alloc((size_t)H_DIM * H3 * sizeof(_Float16));
    // activations
    _Float16* xs16  = (_Float16*)alloc((size_t)N * F_IN * sizeof(_Float16));
    _Float16* a1_16 = (_Float16*)alloc((size_t)N * F_IN * sizeof(_Float16));
    _Float16* h1_16 = (_Float16*)alloc((size_t)N * H_DIM * sizeof(_Float16));
    _Float16* a2_16 = (_Float16*)alloc((size_t)N * H_DIM * sizeof(_Float16));
    float* bufB     = (float*)alloc((size_t)N * H_DIM * sizeof(float));
    _Float16* e16   = (_Float16*)alloc((size_t)N * H_DIM * sizeof(_Float16));
    float* hstate   = (float*)alloc((size_t)N * H_DIM * sizeof(float));
    _Float16* h16   = (_Float16*)alloc((size_t)N * H_DIM * sizeof(_Float16));
    float* gi       = (float*)alloc((size_t)N * H3 * sizeof(float));
    float* gh       = (float*)alloc((size_t)N * H3 * sizeof(float));

    const int TB = 256;
    hipLaunchKernelGGL(init_deg_kernel, dim3((N + TB - 1) / TB), dim3(TB), 0, stream, deg, indeg, N);
    hipLaunchKernelGGL(accum_deg_kernel, dim3((E + TB - 1) / TB), dim3(TB), 0, stream, src, dst, ew, deg, indeg, E);
    hipLaunchKernelGGL(dinv_kernel, dim3((N + TB - 1) / TB), dim3(TB), 0, stream, deg, selfnorm, N);
    hipLaunchKernelGGL(edge_norm_kernel, dim3((E + TB - 1) / TB), dim3(TB), 0, stream, src, dst, ew, deg, norm, E);
    hipLaunchKernelGGL(scan_kernel, dim3(1), dim3(1024), 0, stream, indeg, offs, cursor, N);
    hipLaunchKernelGGL(csr_fill_kernel, dim3((E + TB - 1) / TB), dim3(TB), 0, stream, src, dst, norm, cursor, csr_src, csr_norm, E);

    // weight packs (fp16)
    {
        int tot = (F_IN / 8) * H_DIM;
        hipLaunchKernelGGL(pack_b16_kernel, dim3((tot + TB - 1) / TB), dim3(TB), 0, stream, W1, W1p, F_IN, H_DIM, 0);
        tot = (H_DIM / 8) * H_DIM;
        hipLaunchKernelGGL(pack_b16_kernel, dim3((tot + TB - 1) / TB), dim3(TB), 0, stream, W2, W2p, H_DIM, H_DIM, 0);
        tot = (H_DIM / 8) * H3;
        hipLaunchKernelGGL(pack_b16_kernel, dim3((tot + TB - 1) / TB), dim3(TB), 0, stream, Wih, Wihp, H_DIM, H3, 1);
        hipLaunchKernelGGL(pack_b16_kernel, dim3((tot + TB - 1) / TB), dim3(TB), 0, stream, Whh, Whhp, H_DIM, H3, 1);
    }

    hipMemsetAsync(hstate, 0, (size_t)N * H_DIM * sizeof(float), stream);
    hipMemsetAsync(h16, 0, (size_t)N * H_DIM * sizeof(_Float16), stream);

    const int GM = (N + 127) / 128;  // 157
    dim3 gb(256);
    dim3 g_conv(GM, H_DIM / 128);    // (157, 2)
    dim3 g_gru(GM, H3 / 128);        // (157, 6)

    for (int t = 0; t < T_STEPS; t++) {
        const float* xt = x + (size_t)t * N * F_IN;
        // x -> fp16
        hipLaunchKernelGGL(tofp16_kernel, dim3((N * F_IN / 4 + TB - 1) / TB), dim3(TB), 0, stream,
                           xt, xs16, N * F_IN / 4);
        // agg1: a1 = A @ x   (64-dim gather, exact commute)
        hipLaunchKernelGGL(agg1_kernel, dim3((N + 3) / 4), dim3(256), 0, stream,
                           xs16, offs, csr_src, csr_norm, selfnorm, a1_16, N);
        // conv1: h1 = leaky(a1 @ W1 + b1) -> fp16
        hipLaunchKernelGGL((gemm_f16_kernel<1>), g_conv, gb, 0, stream,
                           a1_16, W1p, b1, (float*)nullptr, h1_16, N, H_DIM, F_IN);
        // agg2: a2 = A @ h1  (256-dim fp16 gather, exact commute)
        hipLaunchKernelGGL(agg2_kernel, dim3((N + 1) / 2), dim3(256), 0, stream,
                           h1_16, offs, csr_src, csr_norm, selfnorm, a2_16, N);
        // conv2: bufB = a2 @ W2 + b2
        hipLaunchKernelGGL((gemm_f16_kernel<0>), g_conv, gb, 0, stream,
                           a2_16, W2p, b2, bufB, (_Float16*)nullptr, N, H_DIM, H_DIM);
        // layernorm -> e16
        hipLaunchKernelGGL(layernorm_kernel, dim3(N), dim3(H_DIM), 0, stream, bufB, lnw, lnb, e16);
        // gi = enc @ Wih^T + bih
        hipLaunchKernelGGL((gemm_f16_kernel<0>), g_gru, gb, 0, stream,
                           e16, Wihp, bih, gi, (_Float16*)nullptr, N, H3, H_DIM);
        // gh = h @ Whh^T + bhh
        hipLaunchKernelGGL((gemm_f16_kernel<0>), g_gru, gb, 0, stream,
                           h16, Whhp, bhh, gh, (_Float16*)nullptr, N, H3, H_DIM);
        hipLaunchKernelGGL(gru_pw_kernel, dim3((N * H_DIM + TB - 1) / TB), dim3(TB), 0, stream,
                           gi, gh, hstate, h16);
    }

    hipLaunchKernelGGL(fc_kernel, dim3((N + 3) / 4), dim3(256), 0, stream, hstate, Wfc, bfc, (float*)d_out, N);
}

// Round 5
// 3797.697 us; speedup vs baseline: 2.9336x; 1.4547x over previous
//
#include <hip/hip_runtime.h>
#include <math.h>

// Problem constants (fixed by reference)
#define T_STEPS 24
#define N_NODES 20000
#define F_IN 64
#define H_DIM 256
#define H3 (3 * H_DIM)
#define TC 4                    // timestep chunk for the encoder
#define NCHUNK (T_STEPS / TC)   // 6

using f16x8 = __attribute__((ext_vector_type(8))) _Float16;
using f16x4 = __attribute__((ext_vector_type(4))) _Float16;
using f16x2 = __attribute__((ext_vector_type(2))) _Float16;
using f32x4 = __attribute__((ext_vector_type(4))) float;

__device__ __forceinline__ void gload_lds16(const void* g, void* l) {
    __builtin_amdgcn_global_load_lds(
        (const __attribute__((address_space(1))) void*)(uintptr_t)g,
        (__attribute__((address_space(3))) void*)l, 16, 0, 0);
}

// ---------------------------------------------------------------------------
// Norm / CSR build kernels
// ---------------------------------------------------------------------------
__global__ void init_deg_kernel(float* deg, int* indeg, int n) {
    int i = blockIdx.x * blockDim.x + threadIdx.x;
    if (i < n) { deg[i] = 1.0f; indeg[i] = 0; }
}

__global__ void accum_deg_kernel(const int* __restrict__ src, const int* __restrict__ dst,
                                 const float* __restrict__ ew, float* deg, int* indeg, int E) {
    int e = blockIdx.x * blockDim.x + threadIdx.x;
    if (e < E) {
        atomicAdd(&deg[dst[e]], ew[e]);
        atomicAdd(&indeg[dst[e]], 1);
    }
}

__global__ void dinv_kernel(float* deg, float* selfnorm, int n) {
    int i = blockIdx.x * blockDim.x + threadIdx.x;
    if (i < n) {
        float d = deg[i];
        float di = (d > 0.0f) ? rsqrtf(d) : 0.0f;
        deg[i] = di;
        selfnorm[i] = di * di;
    }
}

__global__ void edge_norm_kernel(const int* __restrict__ src, const int* __restrict__ dst,
                                 const float* __restrict__ ew, const float* __restrict__ dinv,
                                 float* norm, int E) {
    int e = blockIdx.x * blockDim.x + threadIdx.x;
    if (e < E) norm[e] = dinv[src[e]] * ew[e] * dinv[dst[e]];
}

__global__ void scan_kernel(const int* __restrict__ indeg, int* offs, int* cursor, int N) {
    __shared__ int part[1024];
    int t = threadIdx.x;
    const int CH = (N + 1023) / 1024;
    int s = 0;
    for (int i = 0; i < CH; i++) {
        int idx = t * CH + i;
        if (idx < N) s += indeg[idx];
    }
    part[t] = s;
    __syncthreads();
    for (int off = 1; off < 1024; off <<= 1) {
        int v = (t >= off) ? part[t - off] : 0;
        __syncthreads();
        part[t] += v;
        __syncthreads();
    }
    int base = (t == 0) ? 0 : part[t - 1];
    for (int i = 0; i < CH; i++) {
        int idx = t * CH + i;
        if (idx < N) {
            offs[idx] = base;
            cursor[idx] = base;
            base += indeg[idx];
        }
    }
    if (t == 0) offs[N] = part[1023];
}

__global__ void csr_fill_kernel(const int* __restrict__ src, const int* __restrict__ dst,
                                const float* __restrict__ norm, int* cursor,
                                int* csr_src, float* csr_norm, int E) {
    int e = blockIdx.x * blockDim.x + threadIdx.x;
    if (e < E) {
        int d = dst[e];
        int pos = atomicAdd(&cursor[d], 1);
        csr_src[pos] = src[e];
        csr_norm[pos] = norm[e];
    }
}

// ---------------------------------------------------------------------------
// Weight pack (fp16): P[kk][n][j], j=0..7, kk=k/8.
// trans=0: B = W [K,N] row-major.  trans=1: B = W^T with W [N,K] row-major.
// ---------------------------------------------------------------------------
__global__ void pack_b16_kernel(const float* __restrict__ W, _Float16* __restrict__ P,
                                int K, int Nn, int trans) {
    int idx = blockIdx.x * blockDim.x + threadIdx.x;
    int total = (K >> 3) * Nn;
    if (idx >= total) return;
    int kk = idx / Nn, n = idx - kk * Nn;
    size_t o = (size_t)idx * 8;
    for (int j = 0; j < 8; ++j) {
        float v = trans ? W[(size_t)n * K + kk * 8 + j] : W[(size_t)(kk * 8 + j) * Nn + n];
        P[o + j] = (_Float16)v;
    }
}

// fp32 -> fp16 (vectorized x4)
__global__ void tofp16_kernel(const float* __restrict__ in, _Float16* __restrict__ out, int n4) {
    int i = blockIdx.x * blockDim.x + threadIdx.x;
    if (i < n4) {
        float4 v = ((const float4*)in)[i];
        f16x4 o = { (_Float16)v.x, (_Float16)v.y, (_Float16)v.z, (_Float16)v.w };
        ((f16x4*)out)[i] = o;
    }
}

// ---------------------------------------------------------------------------
// agg1 (chunked over TC): out[t][n][f] = selfnorm[n]*x[t][n][f] + sum_e norm*x[t][src][f]
// One wave per node, 4-way edge-parallel, f16x4 loads (128B/edge).
// grid: (N/4, TC), block 256.
// ---------------------------------------------------------------------------
__global__ void agg1_kernel(const _Float16* __restrict__ xs, const int* __restrict__ offs,
                            const int* __restrict__ csr_src, const float* __restrict__ csr_norm,
                            const float* __restrict__ selfnorm,
                            _Float16* __restrict__ out, int N) {
    int t = blockIdx.y;
    int n = blockIdx.x * 4 + (threadIdx.x >> 6);
    int lane = threadIdx.x & 63;
    int fg = lane & 15, ep = lane >> 4;
    const _Float16* xsl = xs + (size_t)t * N * F_IN;
    f32x4 acc = (f32x4){0.f, 0.f, 0.f, 0.f};
    int e0 = offs[n], e1 = offs[n + 1];
    for (int e = e0 + ep; e < e1; e += 4) {
        int s = csr_src[e];
        float w = csr_norm[e];
        f16x4 v = *(const f16x4*)&xsl[(size_t)s * F_IN + fg * 4];
#pragma unroll
        for (int c = 0; c < 4; ++c) acc[c] = fmaf(w, (float)v[c], acc[c]);
    }
#pragma unroll
    for (int c = 0; c < 4; ++c) {
        acc[c] += __shfl_xor(acc[c], 16, 64);
        acc[c] += __shfl_xor(acc[c], 32, 64);
    }
    f16x4 own = *(const f16x4*)&xsl[(size_t)n * F_IN + fg * 4];
    float sn = selfnorm[n];
#pragma unroll
    for (int c = 0; c < 4; ++c) acc[c] = fmaf(sn, (float)own[c], acc[c]);
    if (ep == 0) {
        f16x4 o = { (_Float16)acc[0], (_Float16)acc[1], (_Float16)acc[2], (_Float16)acc[3] };
        *(f16x4*)&out[((size_t)t * N + n) * F_IN + fg * 4] = o;
    }
}

// ---------------------------------------------------------------------------
// agg2 (chunked over TC): 256-dim fp16 gather, one wave per node, f16x4/lane.
// grid: (N/4, TC), block 256.
// ---------------------------------------------------------------------------
__global__ void agg2_kernel(const _Float16* __restrict__ hs, const int* __restrict__ offs,
                            const int* __restrict__ csr_src, const float* __restrict__ csr_norm,
                            const float* __restrict__ selfnorm,
                            _Float16* __restrict__ out, int N) {
    int t = blockIdx.y;
    int n = blockIdx.x * 4 + (threadIdx.x >> 6);
    int lane = threadIdx.x & 63;
    const _Float16* hsl = hs + (size_t)t * N * H_DIM;
    f16x4 own = *(const f16x4*)&hsl[(size_t)n * H_DIM + lane * 4];
    float sn = selfnorm[n];
    f32x4 acc;
#pragma unroll
    for (int c = 0; c < 4; ++c) acc[c] = sn * (float)own[c];
    int e0 = offs[n], e1 = offs[n + 1];
    for (int e = e0; e < e1; e++) {
        int s = csr_src[e];
        float w = csr_norm[e];
        f16x4 v = *(const f16x4*)&hsl[(size_t)s * H_DIM + lane * 4];
#pragma unroll
        for (int c = 0; c < 4; ++c) acc[c] = fmaf(w, (float)v[c], acc[c]);
    }
    f16x4 o = { (_Float16)acc[0], (_Float16)acc[1], (_Float16)acc[2], (_Float16)acc[3] };
    *(f16x4*)&out[((size_t)t * N + n) * H_DIM + lane * 4] = o;
}

// ---------------------------------------------------------------------------
// fp16 MFMA GEMM: C[M,Nn] = A[M,K] @ B[K,Nn] (+bias)
// 128x128 tile, BK=32, 256 threads = 4 waves (2x2), 16x16x32 f16 MFMA.
// EPI 0: fp32 out (+bias). EPI 1: bias + leaky -> fp16. EPI 2: bias -> fp16.
// A: row-major fp16 [M,K]. B packed: [K/8][Nn][8] fp16.
// ---------------------------------------------------------------------------
template <int EPI>
__global__ __launch_bounds__(256, 4)
void gemm_f16_kernel(const _Float16* __restrict__ A, const _Float16* __restrict__ Bp,
                     const float* __restrict__ bias, float* __restrict__ C,
                     _Float16* __restrict__ C16, int M, int Nn, int K) {
    __shared__ _Float16 As[4][128][8];
    __shared__ _Float16 Bs[4][128][8];

    const int tid = threadIdx.x;
    const int wave = tid >> 6, lane = tid & 63;
    const int bm = blockIdx.x * 128, bn = blockIdx.y * 128;
    const int wm = (wave >> 1) * 64, wn = (wave & 1) * 64;
    const int kq = lane >> 4, r = lane & 15;

    f32x4 acc[4][4];
#pragma unroll
    for (int i = 0; i < 4; ++i)
#pragma unroll
        for (int j = 0; j < 4; ++j) acc[i][j] = (f32x4){0.f, 0.f, 0.f, 0.f};

    for (int k0 = 0; k0 < K; k0 += 32) {
        __syncthreads();
        const int kb = k0 >> 3;
#pragma unroll
        for (int it = 0; it < 2; ++it) {
            int c = it * 256 + tid;          // cell 0..511: kk = c>>7, idx = c&127
            int kk = c >> 7, idx = c & 127;
            int row = bm + idx;
            if (row >= M) row = M - 1;
            size_t aoff = (size_t)row * K + k0 + kk * 8;
            size_t boff = ((size_t)(kb + kk) * Nn + bn + idx) * 8;
            int lbase = (it * 256 + wave * 64) * 8;   // fp16 units, wave-uniform
            gload_lds16(A + aoff, &As[0][0][0] + lbase);
            gload_lds16(Bp + boff, &Bs[0][0][0] + lbase);
        }
        __syncthreads();

        f16x8 a[4], b[4];
#pragma unroll
        for (int f = 0; f < 4; ++f) {
            a[f] = *(const f16x8*)&As[kq][wm + f * 16 + r][0];
            b[f] = *(const f16x8*)&Bs[kq][wn + f * 16 + r][0];
        }
#pragma unroll
        for (int i = 0; i < 4; ++i)
#pragma unroll
            for (int j = 0; j < 4; ++j)
                acc[i][j] = __builtin_amdgcn_mfma_f32_16x16x32_f16(a[i], b[j], acc[i][j], 0, 0, 0);
    }

    // C/D layout: col = lane&15, row = (lane>>4)*4 + reg  [m89]
#pragma unroll
    for (int j = 0; j < 4; ++j) {
        int col = bn + wn + j * 16 + r;
        float bv = bias ? bias[col] : 0.0f;
#pragma unroll
        for (int i = 0; i < 4; ++i) {
#pragma unroll
            for (int q = 0; q < 4; ++q) {
                int row = bm + wm + i * 16 + kq * 4 + q;
                if (row < M) {
                    float v = acc[i][j][q] + bv;
                    if (EPI == 1) {
                        v = (v >= 0.0f) ? v : 0.01f * v;
                        C16[(size_t)row * Nn + col] = (_Float16)v;
                    } else if (EPI == 2) {
                        C16[(size_t)row * Nn + col] = (_Float16)v;
                    } else {
                        C[(size_t)row * Nn + col] = v;
                    }
                }
            }
        }
    }
}

// ---------------------------------------------------------------------------
// LayerNorm over 256 features -> fp16 output. grid = TC*N blocks.
// ---------------------------------------------------------------------------
__global__ void layernorm_kernel(const float* __restrict__ in, const float* __restrict__ w,
                                 const float* __restrict__ b, _Float16* __restrict__ out) {
    int n = blockIdx.x;
    int f = threadIdx.x;
    float v = in[(size_t)n * H_DIM + f];
    float s = v, s2 = v * v;
#pragma unroll
    for (int o = 32; o > 0; o >>= 1) {
        s += __shfl_down(s, o, 64);
        s2 += __shfl_down(s2, o, 64);
    }
    __shared__ float ps[4], ps2[4];
    int wid = f >> 6;
    if ((f & 63) == 0) { ps[wid] = s; ps2[wid] = s2; }
    __syncthreads();
    float S = ps[0] + ps[1] + ps[2] + ps[3];
    float S2 = ps2[0] + ps2[1] + ps2[2] + ps2[3];
    float mu = S * (1.0f / H_DIM);
    float var = S2 * (1.0f / H_DIM) - mu * mu;
    float rstd = rsqrtf(var + 1e-5f);
    float outv = (v - mu) * rstd * w[f] + b[f];
    out[(size_t)n * H_DIM + f] = (_Float16)outv;
}

// ---------------------------------------------------------------------------
// GRU pointwise (fp16 gi/gh/h), 2 features per thread.
// ---------------------------------------------------------------------------
__device__ __forceinline__ float sigmoidf_(float x) { return 1.0f / (1.0f + expf(-x)); }

__global__ void gru_pw_kernel(const _Float16* __restrict__ gi, const _Float16* __restrict__ gh,
                              _Float16* __restrict__ h16) {
    int idx = blockIdx.x * blockDim.x + threadIdx.x;   // pair index
    if (idx >= N_NODES * (H_DIM / 2)) return;
    int n = idx >> 7;
    int j = (idx & 127) * 2;
    const _Float16* gin = gi + (size_t)n * H3;
    const _Float16* ghn = gh + (size_t)n * H3;
    f16x2 ir2 = *(const f16x2*)&gin[j];
    f16x2 iz2 = *(const f16x2*)&gin[H_DIM + j];
    f16x2 in2 = *(const f16x2*)&gin[2 * H_DIM + j];
    f16x2 hr2 = *(const f16x2*)&ghn[j];
    f16x2 hz2 = *(const f16x2*)&ghn[H_DIM + j];
    f16x2 hn2 = *(const f16x2*)&ghn[2 * H_DIM + j];
    f16x2 hp2 = *(const f16x2*)&h16[(size_t)n * H_DIM + j];
    f16x2 o;
#pragma unroll
    for (int c = 0; c < 2; ++c) {
        float r = sigmoidf_((float)ir2[c] + (float)hr2[c]);
        float z = sigmoidf_((float)iz2[c] + (float)hz2[c]);
        float nn = tanhf((float)in2[c] + r * (float)hn2[c]);
        float hv = (1.0f - z) * nn + z * (float)hp2[c];
        o[c] = (_Float16)hv;
    }
    *(f16x2*)&h16[(size_t)n * H_DIM + j] = o;
}

// ---------------------------------------------------------------------------
// fc: out[n] = dot(h16[n,:], Wfc[0,:]) + bfc
// ---------------------------------------------------------------------------
__global__ void fc_kernel(const _Float16* __restrict__ h, const float* __restrict__ Wfc,
                          const float* __restrict__ bfc, float* __restrict__ out, int N) {
    int n = blockIdx.x * 4 + (threadIdx.x >> 6);
    int lane = threadIdx.x & 63;
    if (n >= N) return;
    f16x4 hv = *(const f16x4*)&h[(size_t)n * H_DIM + lane * 4];
    float4 wv = *(const float4*)&Wfc[lane * 4];
    float acc = (float)hv[0] * wv.x + (float)hv[1] * wv.y + (float)hv[2] * wv.z + (float)hv[3] * wv.w;
#pragma unroll
    for (int o = 32; o > 0; o >>= 1) acc += __shfl_down(acc, o, 64);
    if (lane == 0) out[n] = acc + bfc[0];
}

// ---------------------------------------------------------------------------
// Launch
// ---------------------------------------------------------------------------
extern "C" void kernel_launch(void* const* d_in, const int* in_sizes, int n_in,
                              void* d_out, int out_size, void* d_ws, size_t ws_size,
                              hipStream_t stream) {
    const float* x   = (const float*)d_in[0];
    const int* eidx  = (const int*)d_in[1];
    const float* ew  = (const float*)d_in[2];
    const float* W1  = (const float*)d_in[3];
    const float* b1  = (const float*)d_in[4];
    const float* W2  = (const float*)d_in[5];
    const float* b2  = (const float*)d_in[6];
    const float* lnw = (const float*)d_in[7];
    const float* lnb = (const float*)d_in[8];
    const float* Wih = (const float*)d_in[9];
    const float* Whh = (const float*)d_in[10];
    const float* bih = (const float*)d_in[11];
    const float* bhh = (const float*)d_in[12];
    const float* Wfc = (const float*)d_in[13];
    const float* bfc = (const float*)d_in[14];

    const int E = in_sizes[2];
    const int N = N_NODES;
    const int* src = eidx;
    const int* dst = eidx + E;

    uintptr_t p = (uintptr_t)d_ws;
    auto alloc = [&](size_t bytes) -> void* {
        p = (p + 255) & ~(uintptr_t)255;
        void* r = (void*)p;
        p += bytes;
        return r;
    };
    // CSR / norm (~4.2 MB)
    float* deg      = (float*)alloc(N * sizeof(float));
    float* selfnorm = (float*)alloc(N * sizeof(float));
    float* norm     = (float*)alloc(E * sizeof(float));
    int* indeg      = (int*)alloc(N * sizeof(int));
    int* offs       = (int*)alloc((N + 1) * sizeof(int));
    int* cursor     = (int*)alloc(N * sizeof(int));
    int* csr_src    = (int*)alloc(E * sizeof(int));
    float* csr_norm = (float*)alloc(E * sizeof(float));
    // packed fp16 weights (~1 MB)
    _Float16* W1p   = (_Float16*)alloc((size_t)F_IN * H_DIM * sizeof(_Float16));
    _Float16* W2p   = (_Float16*)alloc((size_t)H_DIM * H_DIM * sizeof(_Float16));
    _Float16* Wihp  = (_Float16*)alloc((size_t)H_DIM * H3 * sizeof(_Float16));
    _Float16* Whhp  = (_Float16*)alloc((size_t)H_DIM * H3 * sizeof(_Float16));
    // chunk activations (TC timesteps)
    _Float16* xs16  = (_Float16*)alloc((size_t)TC * N * F_IN * sizeof(_Float16));   // 10.2 MB
    _Float16* a1_16 = (_Float16*)alloc((size_t)TC * N * F_IN * sizeof(_Float16));   // 10.2 MB
    _Float16* h1_16 = (_Float16*)alloc((size_t)TC * N * H_DIM * sizeof(_Float16));  // 41 MB
    _Float16* a2_16 = (_Float16*)alloc((size_t)TC * N * H_DIM * sizeof(_Float16));  // 41 MB
    float* bufB     = (float*)alloc((size_t)TC * N * H_DIM * sizeof(float));        // 82 MB
    _Float16* e16   = (_Float16*)alloc((size_t)TC * N * H_DIM * sizeof(_Float16));  // 41 MB
    _Float16* gi16  = (_Float16*)alloc((size_t)TC * N * H3 * sizeof(_Float16));     // 123 MB
    // recurrent state
    _Float16* h16   = (_Float16*)alloc((size_t)N * H_DIM * sizeof(_Float16));       // 10.2 MB
    _Float16* gh16  = (_Float16*)alloc((size_t)N * H3 * sizeof(_Float16));          // 30.7 MB

    const int TB = 256;
    hipLaunchKernelGGL(init_deg_kernel, dim3((N + TB - 1) / TB), dim3(TB), 0, stream, deg, indeg, N);
    hipLaunchKernelGGL(accum_deg_kernel, dim3((E + TB - 1) / TB), dim3(TB), 0, stream, src, dst, ew, deg, indeg, E);
    hipLaunchKernelGGL(dinv_kernel, dim3((N + TB - 1) / TB), dim3(TB), 0, stream, deg, selfnorm, N);
    hipLaunchKernelGGL(edge_norm_kernel, dim3((E + TB - 1) / TB), dim3(TB), 0, stream, src, dst, ew, deg, norm, E);
    hipLaunchKernelGGL(scan_kernel, dim3(1), dim3(1024), 0, stream, indeg, offs, cursor, N);
    hipLaunchKernelGGL(csr_fill_kernel, dim3((E + TB - 1) / TB), dim3(TB), 0, stream, src, dst, norm, cursor, csr_src, csr_norm, E);

    // weight packs (fp16)
    {
        int tot = (F_IN / 8) * H_DIM;
        hipLaunchKernelGGL(pack_b16_kernel, dim3((tot + TB - 1) / TB), dim3(TB), 0, stream, W1, W1p, F_IN, H_DIM, 0);
        tot = (H_DIM / 8) * H_DIM;
        hipLaunchKernelGGL(pack_b16_kernel, dim3((tot + TB - 1) / TB), dim3(TB), 0, stream, W2, W2p, H_DIM, H_DIM, 0);
        tot = (H_DIM / 8) * H3;
        hipLaunchKernelGGL(pack_b16_kernel, dim3((tot + TB - 1) / TB), dim3(TB), 0, stream, Wih, Wihp, H_DIM, H3, 1);
        hipLaunchKernelGGL(pack_b16_kernel, dim3((tot + TB - 1) / TB), dim3(TB), 0, stream, Whh, Whhp, H_DIM, H3, 1);
    }

    hipMemsetAsync(h16, 0, (size_t)N * H_DIM * sizeof(_Float16), stream);

    const int MC = TC * N;              // 80000 rows per chunk (M = 80000, 80000%128 == 0? 80000/128 = 625 exact)
    dim3 gb(256);
    dim3 g_conv(MC / 128, H_DIM / 128);      // (625, 2)
    dim3 g_gi(MC / 128, H3 / 128);           // (625, 6)
    dim3 g_gh((N + 127) / 128, H3 / 128);    // (157, 6)
    dim3 g_agg(N / 4, TC);                   // (5000, 4)

    for (int chunk = 0; chunk < NCHUNK; ++chunk) {
        const float* xc = x + (size_t)chunk * TC * N * F_IN;
        // x -> fp16 (whole chunk)
        int n4 = TC * N * F_IN / 4;
        hipLaunchKernelGGL(tofp16_kernel, dim3((n4 + TB - 1) / TB), dim3(TB), 0, stream, xc, xs16, n4);
        // agg1 (chunk): a1 = A @ x
        hipLaunchKernelGGL(agg1_kernel, g_agg, dim3(256), 0, stream,
                           xs16, offs, csr_src, csr_norm, selfnorm, a1_16, N);
        // conv1 (chunk): h1 = leaky(a1 @ W1 + b1) -> fp16
        hipLaunchKernelGGL((gemm_f16_kernel<1>), g_conv, gb, 0, stream,
                           a1_16, W1p, b1, (float*)nullptr, h1_16, MC, H_DIM, F_IN);
        // agg2 (chunk): a2 = A @ h1
        hipLaunchKernelGGL(agg2_kernel, g_agg, dim3(256), 0, stream,
                           h1_16, offs, csr_src, csr_norm, selfnorm, a2_16, N);
        // conv2 (chunk): bufB = a2 @ W2 + b2 (fp32)
        hipLaunchKernelGGL((gemm_f16_kernel<0>), g_conv, gb, 0, stream,
                           a2_16, W2p, b2, bufB, (_Float16*)nullptr, MC, H_DIM, H_DIM);
        // layernorm (chunk) -> e16
        hipLaunchKernelGGL(layernorm_kernel, dim3(MC), dim3(H_DIM), 0, stream, bufB, lnw, lnb, e16);
        // gi (chunk) = enc @ Wih^T + bih -> fp16
        hipLaunchKernelGGL((gemm_f16_kernel<2>), g_gi, gb, 0, stream,
                           e16, Wihp, bih, (float*)nullptr, gi16, MC, H3, H_DIM);
        // sequential GRU over the chunk's timesteps
        for (int tc = 0; tc < TC; ++tc) {
            hipLaunchKernelGGL((gemm_f16_kernel<2>), g_gh, gb, 0, stream,
                               h16, Whhp, bhh, (float*)nullptr, gh16, N, H3, H_DIM);
            hipLaunchKernelGGL(gru_pw_kernel, dim3((N * (H_DIM / 2) + TB - 1) / TB), dim3(TB), 0, stream,
                               gi16 + (size_t)tc * N * H3, gh16, h16);
        }
    }

    hipLaunchKernelGGL(fc_kernel, dim3((N + 3) / 4), dim3(256), 0, stream, h16, Wfc, bfc, (float*)d_out, N);
}